// Round 16
// baseline (567.724 us; speedup 1.0000x reference)
//
#include <hip/hip_runtime.h>
#include <hip/hip_bf16.h>
#include <cstdint>
#include <cstddef>

#define N_NODES 20000
#define N_EDGES 40000
#define EPAD 40192             // 157*256, padded edge count
#define N_GRAPHS 800
#define ATOM 64
#define MLP1D 512
#define MLP2D 256
#define NOUT 34

typedef _Float16 h2 __attribute__((ext_vector_type(2)));
typedef _Float16 half8 __attribute__((ext_vector_type(8)));
typedef float f32x4 __attribute__((ext_vector_type(4)));
typedef float f32x16 __attribute__((ext_vector_type(16)));

__device__ __forceinline__ float sigm(float x) { return 1.f / (1.f + expf(-x)); }

// ---------------- fused prep: lin + heprep + Bg-build + misc ----------------
#define LIN_BLKS 5000
#define HEP_BLKS (EPAD / 64)                  // 628
#define BF_TOTAL (129 * 4096)                 // 528384
#define BF_BLKS ((BF_TOTAL + 255) / 256)      // 2064
#define MISC_TOTAL (12288 + 12288 + 32768 + 16384 + EPAD + (N_GRAPHS + 1) + N_EDGES)
#define MISC_BLKS ((MISC_TOTAL + 255) / 256)
#define PREP_BLKS (LIN_BLKS + HEP_BLKS + BF_BLKS + MISC_BLKS)

__global__ __launch_bounds__(256) void prep_all(
    const float* __restrict__ x_feat, const float* __restrict__ W_lin,
    const float* __restrict__ b_lin, float* __restrict__ hx, _Float16* __restrict__ xh,
    const float* __restrict__ ea, const float* __restrict__ W_e1,
    const float* __restrict__ b_e1, _Float16* __restrict__ heT,
    const float* __restrict__ We2, const float* __restrict__ be2, _Float16* __restrict__ Bg,
    const float* __restrict__ gWih, const float* __restrict__ gWhh,
    const float* __restrict__ lWih, const float* __restrict__ lWhh,
    float* __restrict__ gWih4, float* __restrict__ gWhh4,
    float* __restrict__ lWih4, float* __restrict__ lWhh4,
    const int* __restrict__ batch, int* __restrict__ gstart,
    const int* __restrict__ dst, float* __restrict__ deg) {
    int bx = blockIdx.x;
    if (bx < LIN_BLKS) {
        __shared__ float xr[4][64];
        int ln = threadIdx.x >> 6, j = threadIdx.x & 63;
        int n = (bx << 2) + ln;
        xr[ln][j] = x_feat[(size_t)n * 64 + j];
        __syncthreads();
        float acc = b_lin[j];
        for (int i = 0; i < 64; ++i) acc = fmaf(xr[ln][i], W_lin[i * 64 + j], acc);
        float r = fmaxf(acc, 0.f);
        hx[(size_t)n * 64 + j] = r;
        xh[(size_t)n * 64 + j] = (_Float16)r;
        return;
    }
    bx -= LIN_BLKS;
    if (bx < HEP_BLKS) {
        __shared__ float eaL[64 * 17];
        int e0 = bx * 64;
        for (int idx = threadIdx.x; idx < 1024; idx += 256) {
            int r = idx >> 4, i = idx & 15;
            int e = e0 + r;
            eaL[r * 17 + i] = (e < N_EDGES) ? ea[(size_t)e * 16 + i] : 0.f;
        }
        __syncthreads();
        int w = threadIdx.x >> 6, lane = threadIdx.x & 63;
        for (int c = w; c < 128; c += 4) {
            float acc = b_e1[c];
            #pragma unroll
            for (int i = 0; i < 16; ++i)
                acc = fmaf(eaL[lane * 17 + i], W_e1[i * 128 + c], acc);
            heT[(size_t)c * EPAD + e0 + lane] = (_Float16)fmaxf(acc, 0.f);
        }
        return;
    }
    bx -= HEP_BLKS;
    if (bx < BF_BLKS) {
        // Bg[c][kc][ft][lane][8] fp16 for 32x32x16 MFMA:
        // value = W_c[k][f], k = kc*16 + (lane>>5)*8 + j, f = ft*32 + (lane&31)
        int idx = bx * 256 + threadIdx.x;
        if (idx >= BF_TOTAL) return;
        int j = idx & 7, lane = (idx >> 3) & 63, ft = (idx >> 9) & 1;
        int kc = (idx >> 10) & 3, c = idx >> 12;
        int k = kc * 16 + (lane >> 5) * 8 + j;
        int f = ft * 32 + (lane & 31);
        float v = (c < 128) ? We2[(size_t)c * 4096 + k * 64 + f] : be2[k * 64 + f];
        Bg[idx] = (_Float16)v;
        return;
    }
    bx -= BF_BLKS;
    {
        int i = bx * 256 + threadIdx.x;
        // gWih4[(ib*192+t)*4+j] = gWih[t*64 + ib*4 + j], ib in [0,16)
        if (i < 12288) { int j = i & 3; int rest = i >> 2; int t = rest % 192; int ib = rest / 192;
                         gWih4[i] = gWih[t * 64 + ib * 4 + j]; return; }
        i -= 12288;
        if (i < 12288) { int j = i & 3; int rest = i >> 2; int t = rest % 192; int ib = rest / 192;
                         gWhh4[i] = gWhh[t * 64 + ib * 4 + j]; return; }
        i -= 12288;
        // lWih4[(ib*256+t)*4+j] = lWih[t*128 + ib*4 + j], ib in [0,32)
        if (i < 32768) { int j = i & 3; int rest = i >> 2; int t = rest & 255; int ib = rest >> 8;
                         lWih4[i] = lWih[t * 128 + ib * 4 + j]; return; }
        i -= 32768;
        // lWhh4[(ib*256+t)*4+j] = lWhh[t*64 + ib*4 + j], ib in [0,16)
        if (i < 16384) { int j = i & 3; int rest = i >> 2; int t = rest & 255; int ib = rest >> 8;
                         lWhh4[i] = lWhh[t * 64 + ib * 4 + j]; return; }
        i -= 16384;
        if (i < EPAD) { heT[(size_t)128 * EPAD + i] = (_Float16)1.0f; return; }
        i -= EPAD;
        if (i <= N_GRAPHS) {
            if (i == N_GRAPHS) { gstart[i] = N_NODES; return; }
            int lo = 0, hi = N_NODES;
            while (lo < hi) { int mid = (lo + hi) >> 1; if (batch[mid] < i) lo = mid + 1; else hi = mid; }
            gstart[i] = lo;
            return;
        }
        i -= (N_GRAPHS + 1);
        if (i < N_EDGES) { atomicAdd(&deg[dst[i]], 1.f); return; }
    }
}

// ---------------- message passing v11: 32x32x16 MFMA, depth-3 prefetch, KS=4 ----------------
// msg[e,f] = sum_c he[e,c] * (x[src_e] @ W_c)[f]; he folded into A-frag.
// Block = 4 waves = 128 edges x one 32-f half. Depth-3 circular register prefetch
// (B0/B1/B2, statically indexed) gives each L2 load ~3 COMP-durations to land;
// KS=4 c-split -> 5024 blocks (~4.9 waves/SIMD). Exact-once COMP per c (traced for
// nc in {32,33,64,65}); <=2 dead wrapped loads/wave.
__global__ __launch_bounds__(256) void msg_v11(
    const _Float16* __restrict__ Bg, const _Float16* __restrict__ heT,
    const _Float16* __restrict__ xh, const int* __restrict__ src,
    const int* __restrict__ dst, float* __restrict__ agg)
{
    int tid = threadIdx.x;
    int w = tid >> 6, lane = tid & 63;
    int l5 = lane >> 5, l31 = lane & 31;
    int bx = blockIdx.x;
    int ft = bx & 1;                       // f half: 0 or 1
    int eg = bx >> 1;                      // 0..313
    int m0 = eg * 128 + w * 32;            // wave's 32 edges
    int KS = gridDim.y, ks = blockIdx.y;
    int c0 = (129 * ks) / KS;
    int c1 = (129 * (ks + 1)) / KS;
    int nc = c1 - c0;

    // persistent x[src] fragment: row = l31, k = kc*16 + l5*8 + j
    union XU { h2 p[4]; half8 v; } xf[4];
    {
        int e = m0 + l31;
        const _Float16* xp = xh + (size_t)src[e] * 64 + l5 * 8;
        xf[0].v = *(const half8*)(xp);
        xf[1].v = *(const half8*)(xp + 16);
        xf[2].v = *(const half8*)(xp + 32);
        xf[3].v = *(const half8*)(xp + 48);
    }

    f32x16 acc = {};
    const _Float16* bbase = Bg + ft * 512 + lane * 8;
    const _Float16* hbase = heT + m0 + l31;

    half8 B0[4], B1[4], B2[4];
    _Float16 hp0, hp1, hp2;

    auto LOADB = [&](int c, half8* bb, _Float16& hh) {
        const _Float16* bp = bbase + c * 4096;
        bb[0] = *(const half8*)(bp);
        bb[1] = *(const half8*)(bp + 1024);
        bb[2] = *(const half8*)(bp + 2048);
        bb[3] = *(const half8*)(bp + 3072);
        hh = hbase[c * EPAD];
    };
    auto COMP = [&](const half8* bb, _Float16 hh) {
        h2 hv = (h2){hh, hh};
        #pragma unroll
        for (int kc = 0; kc < 4; ++kc) {
            union XU a;
            #pragma unroll
            for (int j = 0; j < 4; ++j) a.p[j] = hv * xf[kc].p[j];
            acc = __builtin_amdgcn_mfma_f32_32x32x16_f16(a.v, bb[kc], acc, 0, 0, 0);
        }
    };
    auto nxt = [&](int i) { return (i + 1 == nc) ? 0 : i + 1; };

    int cur = bx % nc;                     // rotated start within slice
    LOADB(c0 + cur, B0, hp0);
    int i1 = nxt(cur); LOADB(c0 + i1, B1, hp1);
    int i2 = nxt(i1);  LOADB(c0 + i2, B2, hp2);
    int ld = nxt(i2);
    int t = 0;
    for (; t + 3 <= nc; t += 3) {
        COMP(B0, hp0); LOADB(c0 + ld, B0, hp0); ld = nxt(ld);
        COMP(B1, hp1); LOADB(c0 + ld, B1, hp1); ld = nxt(ld);
        COMP(B2, hp2); LOADB(c0 + ld, B2, hp2); ld = nxt(ld);
    }
    if (t < nc) { COMP(B0, hp0); ++t; }
    if (t < nc) { COMP(B1, hp1); }

    // scatter: D col = f = ft*32 + l31; row = (r&3) + 8*(r>>2) + 4*l5
    int fc = ft * 32 + l31;
    #pragma unroll
    for (int r = 0; r < 16; ++r) {
        int e = m0 + (r & 3) + 8 * (r >> 2) + 4 * l5;
        if (e < N_EDGES)
            atomicAdd(&agg[(size_t)dst[e] * 64 + fc], acc[r]);
    }
}

// ---------------- GRU v2: gate-per-thread, coalesced float4 weight loads ----------------
__global__ __launch_bounds__(192) void gru_v2(float* __restrict__ agg,
    const float* __restrict__ deg, const float* __restrict__ bconv,
    const float* __restrict__ Wih4, const float* __restrict__ Whh4,
    const float* __restrict__ bih, const float* __restrict__ bhh,
    float* __restrict__ hx, _Float16* __restrict__ xh) {
    __shared__ float mS[4][64], hS[4][64];
    __shared__ float aI[4][192], aH[4][192];
    int t = threadIdx.x;
    int n0 = blockIdx.x << 2;
    for (int idx = t; idx < 256; idx += 192) {
        int n = idx >> 6, j = idx & 63;
        size_t ix = (size_t)(n0 + n) * 64 + j;
        float dg = fmaxf(deg[n0 + n], 1.f);
        float m = fmaxf(agg[ix] / dg + bconv[j], 0.f);
        agg[ix] = 0.f;
        mS[n][j] = m;
        hS[n][j] = hx[ix];
    }
    __syncthreads();
    float bi = bih[t], bh = bhh[t];
    float AI[4], AH[4];
    #pragma unroll
    for (int n = 0; n < 4; ++n) { AI[n] = bi; AH[n] = bh; }
    #pragma unroll
    for (int ib = 0; ib < 16; ++ib) {
        f32x4 wi = *(const f32x4*)(Wih4 + ((ib * 192 + t) << 2));
        f32x4 wh = *(const f32x4*)(Whh4 + ((ib * 192 + t) << 2));
        int i0 = ib * 4;
        #pragma unroll
        for (int n = 0; n < 4; ++n) {
            AI[n] = fmaf(mS[n][i0],     wi[0], AI[n]);
            AI[n] = fmaf(mS[n][i0 + 1], wi[1], AI[n]);
            AI[n] = fmaf(mS[n][i0 + 2], wi[2], AI[n]);
            AI[n] = fmaf(mS[n][i0 + 3], wi[3], AI[n]);
            AH[n] = fmaf(hS[n][i0],     wh[0], AH[n]);
            AH[n] = fmaf(hS[n][i0 + 1], wh[1], AH[n]);
            AH[n] = fmaf(hS[n][i0 + 2], wh[2], AH[n]);
            AH[n] = fmaf(hS[n][i0 + 3], wh[3], AH[n]);
        }
    }
    #pragma unroll
    for (int n = 0; n < 4; ++n) { aI[n][t] = AI[n]; aH[n][t] = AH[n]; }
    __syncthreads();
    for (int idx = t; idx < 256; idx += 192) {
        int n = idx >> 6, j = idx & 63;
        float rr = sigm(aI[n][j] + aH[n][j]);
        float zz = sigm(aI[n][64 + j] + aH[n][64 + j]);
        float nn = tanhf(aI[n][128 + j] + rr * aH[n][128 + j]);
        size_t ix = (size_t)(n0 + n) * 64 + j;
        float h = hS[n][j];
        float hnew = (1.f - zz) * nn + zz * h;
        hx[ix] = hnew;
        xh[ix] = (_Float16)hnew;
    }
}

// ---------------- Set2Set v3: gate-per-thread, coalesced float4 weight loads ----------
__global__ __launch_bounds__(256) void s2s_kernel(const float* __restrict__ x,
    const int* __restrict__ gstart,
    const float* __restrict__ WI4,   // [(ib*256+t)*4+j] = lWih[t][ib*4+j], ib<32
    const float* __restrict__ WH4,   // [(ib*256+t)*4+j] = lWhh[t][ib*4+j], ib<16
    const float* __restrict__ bih, const float* __restrict__ bhh,
    float* __restrict__ qstar) {
    __shared__ float st[192];          // q(0..63), r(64..127), h(128..191)
    __shared__ float gl[256];
    __shared__ float redmax[4], redsum[4];
    __shared__ float raccs[4][64];
    int g = blockIdx.x, t = threadIdx.x;
    int w = t >> 6, j = t & 63;
    int s0 = gstart[g], s1 = gstart[g + 1];
    if (t < 192) st[t] = 0.f;
    float cj = 0.f;
    float bsum = bih[t] + bhh[t];
    __syncthreads();
    for (int s = 0; s < 3; ++s) {
        float a0 = bsum;
        #pragma unroll
        for (int ib = 0; ib < 32; ++ib) {
            f32x4 wv = *(const f32x4*)(WI4 + ((ib * 256 + t) << 2));
            int i0 = ib * 4;
            a0 = fmaf(st[i0],     wv[0], a0);
            a0 = fmaf(st[i0 + 1], wv[1], a0);
            a0 = fmaf(st[i0 + 2], wv[2], a0);
            a0 = fmaf(st[i0 + 3], wv[3], a0);
        }
        #pragma unroll
        for (int ib = 0; ib < 16; ++ib) {
            f32x4 wv = *(const f32x4*)(WH4 + ((ib * 256 + t) << 2));
            int i0 = 128 + ib * 4;
            a0 = fmaf(st[i0],     wv[0], a0);
            a0 = fmaf(st[i0 + 1], wv[1], a0);
            a0 = fmaf(st[i0 + 2], wv[2], a0);
            a0 = fmaf(st[i0 + 3], wv[3], a0);
        }
        gl[t] = a0;
        __syncthreads();
        if (t < 64) {
            float ig = sigm(gl[t]);
            float fg = sigm(gl[64 + t]);
            float cg = tanhf(gl[128 + t]);
            float og = sigm(gl[192 + t]);
            cj = fg * cj + ig * cg;
            float hnew = og * tanhf(cj);
            st[t] = hnew;        // q = h
            st[128 + t] = hnew;  // h
        }
        __syncthreads();
        float hj = st[128 + j];
        float pmax = -3.0e38f;
        for (int n = s0 + w; n < s1; n += 4) {
            float v = x[(size_t)n * 64 + j] * hj;
            for (int o = 32; o; o >>= 1) v += __shfl_xor(v, o);
            pmax = fmaxf(pmax, v);
        }
        if (j == 0) redmax[w] = pmax;
        __syncthreads();
        float emax = fmaxf(fmaxf(redmax[0], redmax[1]), fmaxf(redmax[2], redmax[3]));
        float esum = 0.f, racc = 0.f;
        for (int n = s0 + w; n < s1; n += 4) {
            float xv = x[(size_t)n * 64 + j];
            float v = xv * hj;
            for (int o = 32; o; o >>= 1) v += __shfl_xor(v, o);
            float ww = expf(v - emax);
            esum += ww;
            racc = fmaf(ww, xv, racc);
        }
        raccs[w][j] = racc;
        if (j == 0) redsum[w] = esum;
        __syncthreads();
        if (t < 64) {
            float es = redsum[0] + redsum[1] + redsum[2] + redsum[3];
            st[64 + j] = (raccs[0][j] + raccs[1][j] + raccs[2][j] + raccs[3][j]) / es;
        }
        __syncthreads();
    }
    if (t < 64) {
        qstar[g * 128 + t] = st[t];
        qstar[g * 128 + 64 + t] = st[64 + t];
    }
}

// ---------------- head ----------------
__global__ void bn_kernel(const float* __restrict__ qs, const float* __restrict__ gamma,
                          const float* __restrict__ beta, float* __restrict__ out) {
    int c = blockIdx.x, l = threadIdx.x;
    float s = 0.f, ss = 0.f;
    for (int r = l; r < N_GRAPHS; r += 64) {
        float v = qs[r * 128 + c];
        s += v; ss += v * v;
    }
    for (int o = 32; o; o >>= 1) { s += __shfl_xor(s, o); ss += __shfl_xor(ss, o); }
    float mu = s * (1.f / N_GRAPHS);
    float var = ss * (1.f / N_GRAPHS) - mu * mu;
    float inv = rsqrtf(var + 1e-5f);
    float ga = gamma[c], be = beta[c];
    for (int r = l; r < N_GRAPHS; r += 64)
        out[r * 128 + c] = ga * (qs[r * 128 + c] - mu) * inv + be;
}

__global__ __launch_bounds__(512) void head_fused(const float* __restrict__ bno,
    const float* __restrict__ Wm1, const float* __restrict__ bm1,
    const float* __restrict__ Wm2, const float* __restrict__ bm2,
    const float* __restrict__ Wp, const float* __restrict__ bp,
    float* __restrict__ out) {
    __shared__ float row[128];
    __shared__ float y1[512];
    __shared__ float y2[256];
    int g = blockIdx.x, t = threadIdx.x;
    int rot = (g * 17) & 127;
    if (t < 128) row[t] = bno[g * 128 + t];
    __syncthreads();
    float acc = bm1[t];
    for (int s = 0; s < 128; ++s) {
        int i = (s + rot) & 127;
        acc = fmaf(row[i], Wm1[i * MLP1D + t], acc);
    }
    y1[t] = fmaxf(acc, 0.f);
    __syncthreads();
    if (t < 256) {
        float a2 = bm2[t];
        int rot2 = (g * 31) & 511;
        for (int s = 0; s < 512; ++s) {
            int i = (s + rot2) & 511;
            a2 = fmaf(y1[i], Wm2[i * MLP2D + t], a2);
        }
        y2[t] = fmaxf(a2, 0.f);
    }
    __syncthreads();
    if (t < NOUT) {
        float a3 = bp[t];
        int rot3 = (g * 13) & 255;
        for (int s = 0; s < 256; ++s) {
            int i = (s + rot3) & 255;
            a3 = fmaf(y2[i], Wp[i * NOUT + t], a3);
        }
        out[g * NOUT + t] = a3;
    }
}

// ---------------- launch ----------------
extern "C" void kernel_launch(void* const* d_in, const int* in_sizes, int n_in,
                              void* d_out, int out_size, void* d_ws, size_t ws_size,
                              hipStream_t stream) {
    (void)in_sizes; (void)n_in; (void)out_size; (void)ws_size;
    const float* x_feat    = (const float*)d_in[0];
    const float* edge_attr = (const float*)d_in[1];
    const int*   eidx      = (const int*)d_in[2];
    const int*   batch     = (const int*)d_in[3];
    const float* W_lin = (const float*)d_in[4];
    const float* b_lin = (const float*)d_in[5];
    const float* W_e1  = (const float*)d_in[6];
    const float* b_e1  = (const float*)d_in[7];
    const float* W_e2  = (const float*)d_in[8];
    const float* b_e2  = (const float*)d_in[9];
    const float* b_conv= (const float*)d_in[10];
    const float* gWih  = (const float*)d_in[11];
    const float* gWhh  = (const float*)d_in[12];
    const float* gbih  = (const float*)d_in[13];
    const float* gbhh  = (const float*)d_in[14];
    const float* lWih  = (const float*)d_in[15];
    const float* lWhh  = (const float*)d_in[16];
    const float* lbih  = (const float*)d_in[17];
    const float* lbhh  = (const float*)d_in[18];
    const float* bng   = (const float*)d_in[19];
    const float* bnb   = (const float*)d_in[20];
    const float* Wm1   = (const float*)d_in[21];
    const float* bm1   = (const float*)d_in[22];
    const float* Wm2   = (const float*)d_in[23];
    const float* bm2   = (const float*)d_in[24];
    const float* Wp    = (const float*)d_in[25];
    const float* bp    = (const float*)d_in[26];
    float* out = (float*)d_out;

    const int* src = eidx;
    const int* dst = eidx + N_EDGES;

    char* w = (char*)d_ws;
    size_t off = 0;
    auto alloc = [&](size_t bytes) -> char* {
        char* p = w + off; off += (bytes + 255) & ~(size_t)255; return p;
    };
    _Float16* Bg     = (_Float16*)alloc((size_t)129 * 4096 * 2);     // 1.06 MB
    _Float16* heT    = (_Float16*)alloc((size_t)129 * EPAD * 2);     // 10.4 MB
    _Float16* xh     = (_Float16*)alloc((size_t)N_NODES * 64 * 2);   // 2.56 MB
    float* hx        = (float*)alloc((size_t)N_NODES * 64 * 4);      // 5.12 MB
    float* agg       = (float*)alloc((size_t)N_NODES * 64 * 4);      // 5.12 MB (adjacent to deg)
    float* deg       = (float*)alloc((size_t)N_NODES * 4);
    float* gWih4     = (float*)alloc(192 * 64 * 4);
    float* gWhh4     = (float*)alloc(192 * 64 * 4);
    float* lWih4     = (float*)alloc(256 * 128 * 4);
    float* lWhh4     = (float*)alloc(256 * 64 * 4);
    float* qstar     = (float*)alloc((size_t)N_GRAPHS * 128 * 4);
    int*   gst       = (int*)alloc((N_GRAPHS + 1) * 4);
    float* bno       = (float*)alloc((size_t)N_GRAPHS * 128 * 4);
    // total ~25 MB

    // agg (5,120,000 B, 256-aligned) and deg (80,000 B) are adjacent: one memset
    hipMemsetAsync(agg, 0, (size_t)N_NODES * 64 * 4 + (size_t)N_NODES * 4, stream);

    prep_all<<<PREP_BLKS, 256, 0, stream>>>(
        x_feat, W_lin, b_lin, hx, xh,
        edge_attr, W_e1, b_e1, heT,
        W_e2, b_e2, Bg,
        gWih, gWhh, lWih, lWhh, gWih4, gWhh4, lWih4, lWhh4,
        batch, gst, dst, deg);

    for (int r = 0; r < 3; ++r) {
        msg_v11<<<dim3(628 * 2, 4), 256, 0, stream>>>(Bg, heT, xh, src, dst, agg);
        gru_v2<<<N_NODES / 4, 192, 0, stream>>>(agg, deg, b_conv, gWih4, gWhh4, gbih, gbhh, hx, xh);
    }

    s2s_kernel<<<N_GRAPHS, 256, 0, stream>>>(hx, gst, lWih4, lWhh4, lbih, lbhh, qstar);

    bn_kernel<<<128, 64, 0, stream>>>(qstar, bng, bnb, bno);
    head_fused<<<N_GRAPHS, 512, 0, stream>>>(bno, Wm1, bm1, Wm2, bm2, Wp, bp, out);
}

// Round 17
// 473.465 us; speedup vs baseline: 1.1991x; 1.1991x over previous
//
#include <hip/hip_runtime.h>
#include <hip/hip_bf16.h>
#include <cstdint>
#include <cstddef>

#define N_NODES 20000
#define N_EDGES 40000
#define EPAD 40192             // 157*256, padded edge count
#define N_GRAPHS 800
#define ATOM 64
#define MLP1D 512
#define MLP2D 256
#define NOUT 34

typedef _Float16 h2 __attribute__((ext_vector_type(2)));
typedef _Float16 half8 __attribute__((ext_vector_type(8)));
typedef float f32x4 __attribute__((ext_vector_type(4)));
typedef float f32x16 __attribute__((ext_vector_type(16)));

__device__ __forceinline__ float sigm(float x) { return 1.f / (1.f + expf(-x)); }

// ---------------- fused prep: lin + heprep + Bg-build + misc ----------------
#define LIN_BLKS 5000
#define HEP_BLKS (EPAD / 64)                  // 628
#define BF_TOTAL (129 * 4096)                 // 528384
#define BF_BLKS ((BF_TOTAL + 255) / 256)      // 2064
#define MISC_TOTAL (12288 + 12288 + 32768 + 16384 + EPAD + (N_GRAPHS + 1) + N_EDGES)
#define MISC_BLKS ((MISC_TOTAL + 255) / 256)
#define PREP_BLKS (LIN_BLKS + HEP_BLKS + BF_BLKS + MISC_BLKS)

__global__ __launch_bounds__(256) void prep_all(
    const float* __restrict__ x_feat, const float* __restrict__ W_lin,
    const float* __restrict__ b_lin, float* __restrict__ hx, _Float16* __restrict__ xh,
    const float* __restrict__ ea, const float* __restrict__ W_e1,
    const float* __restrict__ b_e1, _Float16* __restrict__ heT,
    const float* __restrict__ We2, const float* __restrict__ be2, _Float16* __restrict__ Bg,
    const float* __restrict__ gWih, const float* __restrict__ gWhh,
    const float* __restrict__ lWih, const float* __restrict__ lWhh,
    float* __restrict__ gWih4, float* __restrict__ gWhh4,
    float* __restrict__ lWih4, float* __restrict__ lWhh4,
    const int* __restrict__ batch, int* __restrict__ gstart,
    const int* __restrict__ dst, float* __restrict__ deg) {
    int bx = blockIdx.x;
    if (bx < LIN_BLKS) {
        __shared__ float xr[4][64];
        int ln = threadIdx.x >> 6, j = threadIdx.x & 63;
        int n = (bx << 2) + ln;
        xr[ln][j] = x_feat[(size_t)n * 64 + j];
        __syncthreads();
        float acc = b_lin[j];
        for (int i = 0; i < 64; ++i) acc = fmaf(xr[ln][i], W_lin[i * 64 + j], acc);
        float r = fmaxf(acc, 0.f);
        hx[(size_t)n * 64 + j] = r;
        xh[(size_t)n * 64 + j] = (_Float16)r;
        return;
    }
    bx -= LIN_BLKS;
    if (bx < HEP_BLKS) {
        __shared__ float eaL[64 * 17];
        int e0 = bx * 64;
        for (int idx = threadIdx.x; idx < 1024; idx += 256) {
            int r = idx >> 4, i = idx & 15;
            int e = e0 + r;
            eaL[r * 17 + i] = (e < N_EDGES) ? ea[(size_t)e * 16 + i] : 0.f;
        }
        __syncthreads();
        int w = threadIdx.x >> 6, lane = threadIdx.x & 63;
        for (int c = w; c < 128; c += 4) {
            float acc = b_e1[c];
            #pragma unroll
            for (int i = 0; i < 16; ++i)
                acc = fmaf(eaL[lane * 17 + i], W_e1[i * 128 + c], acc);
            heT[(size_t)c * EPAD + e0 + lane] = (_Float16)fmaxf(acc, 0.f);
        }
        return;
    }
    bx -= HEP_BLKS;
    if (bx < BF_BLKS) {
        // Bg[c][kc][ft][lane][8] fp16 for 32x32x16 MFMA:
        // value = W_c[k][f], k = kc*16 + (lane>>5)*8 + j, f = ft*32 + (lane&31)
        int idx = bx * 256 + threadIdx.x;
        if (idx >= BF_TOTAL) return;
        int j = idx & 7, lane = (idx >> 3) & 63, ft = (idx >> 9) & 1;
        int kc = (idx >> 10) & 3, c = idx >> 12;
        int k = kc * 16 + (lane >> 5) * 8 + j;
        int f = ft * 32 + (lane & 31);
        float v = (c < 128) ? We2[(size_t)c * 4096 + k * 64 + f] : be2[k * 64 + f];
        Bg[idx] = (_Float16)v;
        return;
    }
    bx -= BF_BLKS;
    {
        int i = bx * 256 + threadIdx.x;
        // gWih4[(ib*192+t)*4+j] = gWih[t*64 + ib*4 + j], ib in [0,16)
        if (i < 12288) { int j = i & 3; int rest = i >> 2; int t = rest % 192; int ib = rest / 192;
                         gWih4[i] = gWih[t * 64 + ib * 4 + j]; return; }
        i -= 12288;
        if (i < 12288) { int j = i & 3; int rest = i >> 2; int t = rest % 192; int ib = rest / 192;
                         gWhh4[i] = gWhh[t * 64 + ib * 4 + j]; return; }
        i -= 12288;
        // lWih4[(ib*256+t)*4+j] = lWih[t*128 + ib*4 + j], ib in [0,32)
        if (i < 32768) { int j = i & 3; int rest = i >> 2; int t = rest & 255; int ib = rest >> 8;
                         lWih4[i] = lWih[t * 128 + ib * 4 + j]; return; }
        i -= 32768;
        // lWhh4[(ib*256+t)*4+j] = lWhh[t*64 + ib*4 + j], ib in [0,16)
        if (i < 16384) { int j = i & 3; int rest = i >> 2; int t = rest & 255; int ib = rest >> 8;
                         lWhh4[i] = lWhh[t * 64 + ib * 4 + j]; return; }
        i -= 16384;
        if (i < EPAD) { heT[(size_t)128 * EPAD + i] = (_Float16)1.0f; return; }
        i -= EPAD;
        if (i <= N_GRAPHS) {
            if (i == N_GRAPHS) { gstart[i] = N_NODES; return; }
            int lo = 0, hi = N_NODES;
            while (lo < hi) { int mid = (lo + hi) >> 1; if (batch[mid] < i) lo = mid + 1; else hi = mid; }
            gstart[i] = lo;
            return;
        }
        i -= (N_GRAPHS + 1);
        if (i < N_EDGES) { atomicAdd(&deg[dst[i]], 1.f); return; }
    }
}

// ---------------- message passing v12: 32x32x16 MFMA, depth-3 prefetch, KS=4, dual acc ----
// msg[e,f] = sum_c he[e,c] * (x[src_e] @ W_c)[f]; he folded into A-frag.
// Block = 4 waves = 128 edges x one 32-f half (grid 628 = 314 eg x 2 ft; FIXED r16's
// 2x-oversized grid). Depth-3 circular register prefetch; KS=4 c-split (2512 blocks).
// Dual accumulators (kc 0-1 -> accA, kc 2-3 -> accB) halve the MFMA latency chain.
__global__ __launch_bounds__(256) void msg_v12(
    const _Float16* __restrict__ Bg, const _Float16* __restrict__ heT,
    const _Float16* __restrict__ xh, const int* __restrict__ src,
    const int* __restrict__ dst, float* __restrict__ agg)
{
    int tid = threadIdx.x;
    int w = tid >> 6, lane = tid & 63;
    int l5 = lane >> 5, l31 = lane & 31;
    int bx = blockIdx.x;
    int ft = bx & 1;                       // f half: 0 or 1
    int eg = bx >> 1;                      // 0..313
    int m0 = eg * 128 + w * 32;            // wave's 32 edges (< EPAD)
    int KS = gridDim.y, ks = blockIdx.y;
    int c0 = (129 * ks) / KS;
    int c1 = (129 * (ks + 1)) / KS;
    int nc = c1 - c0;

    // persistent x[src] fragment: row = l31, k = kc*16 + l5*8 + j
    union XU { h2 p[4]; half8 v; } xf[4];
    {
        int e = m0 + l31;
        const _Float16* xp = xh + (size_t)src[e] * 64 + l5 * 8;
        xf[0].v = *(const half8*)(xp);
        xf[1].v = *(const half8*)(xp + 16);
        xf[2].v = *(const half8*)(xp + 32);
        xf[3].v = *(const half8*)(xp + 48);
    }

    f32x16 accA = {}, accB = {};
    const _Float16* bbase = Bg + ft * 512 + lane * 8;
    const _Float16* hbase = heT + m0 + l31;

    half8 B0[4], B1[4], B2[4];
    _Float16 hp0, hp1, hp2;

    auto LOADB = [&](int c, half8* bb, _Float16& hh) {
        const _Float16* bp = bbase + c * 4096;
        bb[0] = *(const half8*)(bp);
        bb[1] = *(const half8*)(bp + 1024);
        bb[2] = *(const half8*)(bp + 2048);
        bb[3] = *(const half8*)(bp + 3072);
        hh = hbase[c * EPAD];
    };
    auto COMP = [&](const half8* bb, _Float16 hh) {
        h2 hv = (h2){hh, hh};
        union XU a0, a1, a2, a3;
        #pragma unroll
        for (int j = 0; j < 4; ++j) {
            a0.p[j] = hv * xf[0].p[j];
            a1.p[j] = hv * xf[1].p[j];
            a2.p[j] = hv * xf[2].p[j];
            a3.p[j] = hv * xf[3].p[j];
        }
        accA = __builtin_amdgcn_mfma_f32_32x32x16_f16(a0.v, bb[0], accA, 0, 0, 0);
        accB = __builtin_amdgcn_mfma_f32_32x32x16_f16(a1.v, bb[1], accB, 0, 0, 0);
        accA = __builtin_amdgcn_mfma_f32_32x32x16_f16(a2.v, bb[2], accA, 0, 0, 0);
        accB = __builtin_amdgcn_mfma_f32_32x32x16_f16(a3.v, bb[3], accB, 0, 0, 0);
    };
    auto nxt = [&](int i) { return (i + 1 == nc) ? 0 : i + 1; };

    int cur = bx % nc;                     // rotated start within slice
    LOADB(c0 + cur, B0, hp0);
    int i1 = nxt(cur); LOADB(c0 + i1, B1, hp1);
    int i2 = nxt(i1);  LOADB(c0 + i2, B2, hp2);
    int ld = nxt(i2);
    int t = 0;
    for (; t + 3 <= nc; t += 3) {
        COMP(B0, hp0); LOADB(c0 + ld, B0, hp0); ld = nxt(ld);
        COMP(B1, hp1); LOADB(c0 + ld, B1, hp1); ld = nxt(ld);
        COMP(B2, hp2); LOADB(c0 + ld, B2, hp2); ld = nxt(ld);
    }
    if (t < nc) { COMP(B0, hp0); ++t; }
    if (t < nc) { COMP(B1, hp1); }

    // scatter: D col = f = ft*32 + l31; row = (r&3) + 8*(r>>2) + 4*l5
    int fc = ft * 32 + l31;
    #pragma unroll
    for (int r = 0; r < 16; ++r) {
        int e = m0 + (r & 3) + 8 * (r >> 2) + 4 * l5;
        if (e < N_EDGES)
            atomicAdd(&agg[(size_t)dst[e] * 64 + fc], accA[r] + accB[r]);
    }
}

// ---------------- GRU v2: gate-per-thread, coalesced float4 weight loads ----------------
__global__ __launch_bounds__(192) void gru_v2(float* __restrict__ agg,
    const float* __restrict__ deg, const float* __restrict__ bconv,
    const float* __restrict__ Wih4, const float* __restrict__ Whh4,
    const float* __restrict__ bih, const float* __restrict__ bhh,
    float* __restrict__ hx, _Float16* __restrict__ xh) {
    __shared__ float mS[4][64], hS[4][64];
    __shared__ float aI[4][192], aH[4][192];
    int t = threadIdx.x;
    int n0 = blockIdx.x << 2;
    for (int idx = t; idx < 256; idx += 192) {
        int n = idx >> 6, j = idx & 63;
        size_t ix = (size_t)(n0 + n) * 64 + j;
        float dg = fmaxf(deg[n0 + n], 1.f);
        float m = fmaxf(agg[ix] / dg + bconv[j], 0.f);
        agg[ix] = 0.f;
        mS[n][j] = m;
        hS[n][j] = hx[ix];
    }
    __syncthreads();
    float bi = bih[t], bh = bhh[t];
    float AI[4], AH[4];
    #pragma unroll
    for (int n = 0; n < 4; ++n) { AI[n] = bi; AH[n] = bh; }
    #pragma unroll
    for (int ib = 0; ib < 16; ++ib) {
        f32x4 wi = *(const f32x4*)(Wih4 + ((ib * 192 + t) << 2));
        f32x4 wh = *(const f32x4*)(Whh4 + ((ib * 192 + t) << 2));
        int i0 = ib * 4;
        #pragma unroll
        for (int n = 0; n < 4; ++n) {
            AI[n] = fmaf(mS[n][i0],     wi[0], AI[n]);
            AI[n] = fmaf(mS[n][i0 + 1], wi[1], AI[n]);
            AI[n] = fmaf(mS[n][i0 + 2], wi[2], AI[n]);
            AI[n] = fmaf(mS[n][i0 + 3], wi[3], AI[n]);
            AH[n] = fmaf(hS[n][i0],     wh[0], AH[n]);
            AH[n] = fmaf(hS[n][i0 + 1], wh[1], AH[n]);
            AH[n] = fmaf(hS[n][i0 + 2], wh[2], AH[n]);
            AH[n] = fmaf(hS[n][i0 + 3], wh[3], AH[n]);
        }
    }
    #pragma unroll
    for (int n = 0; n < 4; ++n) { aI[n][t] = AI[n]; aH[n][t] = AH[n]; }
    __syncthreads();
    for (int idx = t; idx < 256; idx += 192) {
        int n = idx >> 6, j = idx & 63;
        float rr = sigm(aI[n][j] + aH[n][j]);
        float zz = sigm(aI[n][64 + j] + aH[n][64 + j]);
        float nn = tanhf(aI[n][128 + j] + rr * aH[n][128 + j]);
        size_t ix = (size_t)(n0 + n) * 64 + j;
        float h = hS[n][j];
        float hnew = (1.f - zz) * nn + zz * h;
        hx[ix] = hnew;
        xh[ix] = (_Float16)hnew;
    }
}

// ---------------- Set2Set v3: gate-per-thread, coalesced float4 weight loads ----------
__global__ __launch_bounds__(256) void s2s_kernel(const float* __restrict__ x,
    const int* __restrict__ gstart,
    const float* __restrict__ WI4,   // [(ib*256+t)*4+j] = lWih[t][ib*4+j], ib<32
    const float* __restrict__ WH4,   // [(ib*256+t)*4+j] = lWhh[t][ib*4+j], ib<16
    const float* __restrict__ bih, const float* __restrict__ bhh,
    float* __restrict__ qstar) {
    __shared__ float st[192];          // q(0..63), r(64..127), h(128..191)
    __shared__ float gl[256];
    __shared__ float redmax[4], redsum[4];
    __shared__ float raccs[4][64];
    int g = blockIdx.x, t = threadIdx.x;
    int w = t >> 6, j = t & 63;
    int s0 = gstart[g], s1 = gstart[g + 1];
    if (t < 192) st[t] = 0.f;
    float cj = 0.f;
    float bsum = bih[t] + bhh[t];
    __syncthreads();
    for (int s = 0; s < 3; ++s) {
        float a0 = bsum;
        #pragma unroll
        for (int ib = 0; ib < 32; ++ib) {
            f32x4 wv = *(const f32x4*)(WI4 + ((ib * 256 + t) << 2));
            int i0 = ib * 4;
            a0 = fmaf(st[i0],     wv[0], a0);
            a0 = fmaf(st[i0 + 1], wv[1], a0);
            a0 = fmaf(st[i0 + 2], wv[2], a0);
            a0 = fmaf(st[i0 + 3], wv[3], a0);
        }
        #pragma unroll
        for (int ib = 0; ib < 16; ++ib) {
            f32x4 wv = *(const f32x4*)(WH4 + ((ib * 256 + t) << 2));
            int i0 = 128 + ib * 4;
            a0 = fmaf(st[i0],     wv[0], a0);
            a0 = fmaf(st[i0 + 1], wv[1], a0);
            a0 = fmaf(st[i0 + 2], wv[2], a0);
            a0 = fmaf(st[i0 + 3], wv[3], a0);
        }
        gl[t] = a0;
        __syncthreads();
        if (t < 64) {
            float ig = sigm(gl[t]);
            float fg = sigm(gl[64 + t]);
            float cg = tanhf(gl[128 + t]);
            float og = sigm(gl[192 + t]);
            cj = fg * cj + ig * cg;
            float hnew = og * tanhf(cj);
            st[t] = hnew;        // q = h
            st[128 + t] = hnew;  // h
        }
        __syncthreads();
        float hj = st[128 + j];
        float pmax = -3.0e38f;
        for (int n = s0 + w; n < s1; n += 4) {
            float v = x[(size_t)n * 64 + j] * hj;
            for (int o = 32; o; o >>= 1) v += __shfl_xor(v, o);
            pmax = fmaxf(pmax, v);
        }
        if (j == 0) redmax[w] = pmax;
        __syncthreads();
        float emax = fmaxf(fmaxf(redmax[0], redmax[1]), fmaxf(redmax[2], redmax[3]));
        float esum = 0.f, racc = 0.f;
        for (int n = s0 + w; n < s1; n += 4) {
            float xv = x[(size_t)n * 64 + j];
            float v = xv * hj;
            for (int o = 32; o; o >>= 1) v += __shfl_xor(v, o);
            float ww = expf(v - emax);
            esum += ww;
            racc = fmaf(ww, xv, racc);
        }
        raccs[w][j] = racc;
        if (j == 0) redsum[w] = esum;
        __syncthreads();
        if (t < 64) {
            float es = redsum[0] + redsum[1] + redsum[2] + redsum[3];
            st[64 + j] = (raccs[0][j] + raccs[1][j] + raccs[2][j] + raccs[3][j]) / es;
        }
        __syncthreads();
    }
    if (t < 64) {
        qstar[g * 128 + t] = st[t];
        qstar[g * 128 + 64 + t] = st[64 + t];
    }
}

// ---------------- head ----------------
__global__ void bn_kernel(const float* __restrict__ qs, const float* __restrict__ gamma,
                          const float* __restrict__ beta, float* __restrict__ out) {
    int c = blockIdx.x, l = threadIdx.x;
    float s = 0.f, ss = 0.f;
    for (int r = l; r < N_GRAPHS; r += 64) {
        float v = qs[r * 128 + c];
        s += v; ss += v * v;
    }
    for (int o = 32; o; o >>= 1) { s += __shfl_xor(s, o); ss += __shfl_xor(ss, o); }
    float mu = s * (1.f / N_GRAPHS);
    float var = ss * (1.f / N_GRAPHS) - mu * mu;
    float inv = rsqrtf(var + 1e-5f);
    float ga = gamma[c], be = beta[c];
    for (int r = l; r < N_GRAPHS; r += 64)
        out[r * 128 + c] = ga * (qs[r * 128 + c] - mu) * inv + be;
}

__global__ __launch_bounds__(512) void head_fused(const float* __restrict__ bno,
    const float* __restrict__ Wm1, const float* __restrict__ bm1,
    const float* __restrict__ Wm2, const float* __restrict__ bm2,
    const float* __restrict__ Wp, const float* __restrict__ bp,
    float* __restrict__ out) {
    __shared__ float row[128];
    __shared__ float y1[512];
    __shared__ float y2[256];
    int g = blockIdx.x, t = threadIdx.x;
    int rot = (g * 17) & 127;
    if (t < 128) row[t] = bno[g * 128 + t];
    __syncthreads();
    float acc = bm1[t];
    for (int s = 0; s < 128; ++s) {
        int i = (s + rot) & 127;
        acc = fmaf(row[i], Wm1[i * MLP1D + t], acc);
    }
    y1[t] = fmaxf(acc, 0.f);
    __syncthreads();
    if (t < 256) {
        float a2 = bm2[t];
        int rot2 = (g * 31) & 511;
        for (int s = 0; s < 512; ++s) {
            int i = (s + rot2) & 511;
            a2 = fmaf(y1[i], Wm2[i * MLP2D + t], a2);
        }
        y2[t] = fmaxf(a2, 0.f);
    }
    __syncthreads();
    if (t < NOUT) {
        float a3 = bp[t];
        int rot3 = (g * 13) & 255;
        for (int s = 0; s < 256; ++s) {
            int i = (s + rot3) & 255;
            a3 = fmaf(y2[i], Wp[i * NOUT + t], a3);
        }
        out[g * NOUT + t] = a3;
    }
}

// ---------------- launch ----------------
extern "C" void kernel_launch(void* const* d_in, const int* in_sizes, int n_in,
                              void* d_out, int out_size, void* d_ws, size_t ws_size,
                              hipStream_t stream) {
    (void)in_sizes; (void)n_in; (void)out_size; (void)ws_size;
    const float* x_feat    = (const float*)d_in[0];
    const float* edge_attr = (const float*)d_in[1];
    const int*   eidx      = (const int*)d_in[2];
    const int*   batch     = (const int*)d_in[3];
    const float* W_lin = (const float*)d_in[4];
    const float* b_lin = (const float*)d_in[5];
    const float* W_e1  = (const float*)d_in[6];
    const float* b_e1  = (const float*)d_in[7];
    const float* W_e2  = (const float*)d_in[8];
    const float* b_e2  = (const float*)d_in[9];
    const float* b_conv= (const float*)d_in[10];
    const float* gWih  = (const float*)d_in[11];
    const float* gWhh  = (const float*)d_in[12];
    const float* gbih  = (const float*)d_in[13];
    const float* gbhh  = (const float*)d_in[14];
    const float* lWih  = (const float*)d_in[15];
    const float* lWhh  = (const float*)d_in[16];
    const float* lbih  = (const float*)d_in[17];
    const float* lbhh  = (const float*)d_in[18];
    const float* bng   = (const float*)d_in[19];
    const float* bnb   = (const float*)d_in[20];
    const float* Wm1   = (const float*)d_in[21];
    const float* bm1   = (const float*)d_in[22];
    const float* Wm2   = (const float*)d_in[23];
    const float* bm2   = (const float*)d_in[24];
    const float* Wp    = (const float*)d_in[25];
    const float* bp    = (const float*)d_in[26];
    float* out = (float*)d_out;

    const int* src = eidx;
    const int* dst = eidx + N_EDGES;

    char* w = (char*)d_ws;
    size_t off = 0;
    auto alloc = [&](size_t bytes) -> char* {
        char* p = w + off; off += (bytes + 255) & ~(size_t)255; return p;
    };
    _Float16* Bg     = (_Float16*)alloc((size_t)129 * 4096 * 2);     // 1.06 MB
    _Float16* heT    = (_Float16*)alloc((size_t)129 * EPAD * 2);     // 10.4 MB
    _Float16* xh     = (_Float16*)alloc((size_t)N_NODES * 64 * 2);   // 2.56 MB
    float* hx        = (float*)alloc((size_t)N_NODES * 64 * 4);      // 5.12 MB
    float* agg       = (float*)alloc((size_t)N_NODES * 64 * 4);      // 5.12 MB (adjacent to deg)
    float* deg       = (float*)alloc((size_t)N_NODES * 4);
    float* gWih4     = (float*)alloc(192 * 64 * 4);
    float* gWhh4     = (float*)alloc(192 * 64 * 4);
    float* lWih4     = (float*)alloc(256 * 128 * 4);
    float* lWhh4     = (float*)alloc(256 * 64 * 4);
    float* qstar     = (float*)alloc((size_t)N_GRAPHS * 128 * 4);
    int*   gst       = (int*)alloc((N_GRAPHS + 1) * 4);
    float* bno       = (float*)alloc((size_t)N_GRAPHS * 128 * 4);
    // total ~25 MB

    // agg (5,120,000 B, 256-aligned) and deg (80,000 B) are adjacent: one memset
    hipMemsetAsync(agg, 0, (size_t)N_NODES * 64 * 4 + (size_t)N_NODES * 4, stream);

    prep_all<<<PREP_BLKS, 256, 0, stream>>>(
        x_feat, W_lin, b_lin, hx, xh,
        edge_attr, W_e1, b_e1, heT,
        W_e2, b_e2, Bg,
        gWih, gWhh, lWih, lWhh, gWih4, gWhh4, lWih4, lWhh4,
        batch, gst, dst, deg);

    for (int r = 0; r < 3; ++r) {
        msg_v12<<<dim3(628, 4), 256, 0, stream>>>(Bg, heT, xh, src, dst, agg);
        gru_v2<<<N_NODES / 4, 192, 0, stream>>>(agg, deg, b_conv, gWih4, gWhh4, gbih, gbhh, hx, xh);
    }

    s2s_kernel<<<N_GRAPHS, 256, 0, stream>>>(hx, gst, lWih4, lWhh4, lbih, lbhh, qstar);

    bn_kernel<<<128, 64, 0, stream>>>(qstar, bng, bnb, bno);
    head_fused<<<N_GRAPHS, 512, 0, stream>>>(bno, Wm1, bm1, Wm2, bm2, Wp, bp, out);
}

// Round 18
// 406.865 us; speedup vs baseline: 1.3954x; 1.1637x over previous
//
#include <hip/hip_runtime.h>
#include <hip/hip_bf16.h>
#include <cstdint>
#include <cstddef>

#define N_NODES 20000
#define N_EDGES 40000
#define EPAD 40192             // 157*256, padded edge count
#define N_GRAPHS 800
#define ATOM 64
#define MLP1D 512
#define MLP2D 256
#define NOUT 34

typedef _Float16 h2 __attribute__((ext_vector_type(2)));
typedef _Float16 half8 __attribute__((ext_vector_type(8)));
typedef float f32x4 __attribute__((ext_vector_type(4)));
typedef float f32x16 __attribute__((ext_vector_type(16)));

__device__ __forceinline__ float sigm(float x) { return 1.f / (1.f + expf(-x)); }

// ---------------- fused prep: lin + heprep + Bg-build + misc ----------------
#define LIN_BLKS 5000
#define HEP_BLKS (EPAD / 64)                  // 628
#define BF_TOTAL (129 * 4096)                 // 528384
#define BF_BLKS ((BF_TOTAL + 255) / 256)      // 2064
#define MISC_TOTAL (12288 + 12288 + 32768 + 16384 + EPAD + (N_GRAPHS + 1) + N_EDGES)
#define MISC_BLKS ((MISC_TOTAL + 255) / 256)
#define PREP_BLKS (LIN_BLKS + HEP_BLKS + BF_BLKS + MISC_BLKS)

__global__ __launch_bounds__(256) void prep_all(
    const float* __restrict__ x_feat, const float* __restrict__ W_lin,
    const float* __restrict__ b_lin, float* __restrict__ hx, _Float16* __restrict__ xh,
    const float* __restrict__ ea, const float* __restrict__ W_e1,
    const float* __restrict__ b_e1, _Float16* __restrict__ heT,
    const float* __restrict__ We2, const float* __restrict__ be2, _Float16* __restrict__ Bg,
    const float* __restrict__ gWih, const float* __restrict__ gWhh,
    const float* __restrict__ lWih, const float* __restrict__ lWhh,
    float* __restrict__ gWih4, float* __restrict__ gWhh4,
    float* __restrict__ lWih4, float* __restrict__ lWhh4,
    const int* __restrict__ batch, int* __restrict__ gstart,
    const int* __restrict__ dst, float* __restrict__ deg) {
    int bx = blockIdx.x;
    if (bx < LIN_BLKS) {
        __shared__ float xr[4][64];
        int ln = threadIdx.x >> 6, j = threadIdx.x & 63;
        int n = (bx << 2) + ln;
        xr[ln][j] = x_feat[(size_t)n * 64 + j];
        __syncthreads();
        float acc = b_lin[j];
        for (int i = 0; i < 64; ++i) acc = fmaf(xr[ln][i], W_lin[i * 64 + j], acc);
        float r = fmaxf(acc, 0.f);
        hx[(size_t)n * 64 + j] = r;
        xh[(size_t)n * 64 + j] = (_Float16)r;
        return;
    }
    bx -= LIN_BLKS;
    if (bx < HEP_BLKS) {
        __shared__ float eaL[64 * 17];
        int e0 = bx * 64;
        for (int idx = threadIdx.x; idx < 1024; idx += 256) {
            int r = idx >> 4, i = idx & 15;
            int e = e0 + r;
            eaL[r * 17 + i] = (e < N_EDGES) ? ea[(size_t)e * 16 + i] : 0.f;
        }
        __syncthreads();
        int w = threadIdx.x >> 6, lane = threadIdx.x & 63;
        for (int c = w; c < 128; c += 4) {
            float acc = b_e1[c];
            #pragma unroll
            for (int i = 0; i < 16; ++i)
                acc = fmaf(eaL[lane * 17 + i], W_e1[i * 128 + c], acc);
            heT[(size_t)c * EPAD + e0 + lane] = (_Float16)fmaxf(acc, 0.f);
        }
        return;
    }
    bx -= HEP_BLKS;
    if (bx < BF_BLKS) {
        // Bg[c][kc][ft][lane][8] fp16 for 32x32x16 MFMA:
        // value = W_c[k][f], k = kc*16 + (lane>>5)*8 + j, f = ft*32 + (lane&31)
        int idx = bx * 256 + threadIdx.x;
        if (idx >= BF_TOTAL) return;
        int j = idx & 7, lane = (idx >> 3) & 63, ft = (idx >> 9) & 1;
        int kc = (idx >> 10) & 3, c = idx >> 12;
        int k = kc * 16 + (lane >> 5) * 8 + j;
        int f = ft * 32 + (lane & 31);
        float v = (c < 128) ? We2[(size_t)c * 4096 + k * 64 + f] : be2[k * 64 + f];
        Bg[idx] = (_Float16)v;
        return;
    }
    bx -= BF_BLKS;
    {
        int i = bx * 256 + threadIdx.x;
        // gWih4[(ib*192+t)*4+j] = gWih[t*64 + ib*4 + j], ib in [0,16)
        if (i < 12288) { int j = i & 3; int rest = i >> 2; int t = rest % 192; int ib = rest / 192;
                         gWih4[i] = gWih[t * 64 + ib * 4 + j]; return; }
        i -= 12288;
        if (i < 12288) { int j = i & 3; int rest = i >> 2; int t = rest % 192; int ib = rest / 192;
                         gWhh4[i] = gWhh[t * 64 + ib * 4 + j]; return; }
        i -= 12288;
        // lWih4[(ib*256+t)*4+j] = lWih[t*128 + ib*4 + j], ib in [0,32)
        if (i < 32768) { int j = i & 3; int rest = i >> 2; int t = rest & 255; int ib = rest >> 8;
                         lWih4[i] = lWih[t * 128 + ib * 4 + j]; return; }
        i -= 32768;
        // lWhh4[(ib*256+t)*4+j] = lWhh[t*64 + ib*4 + j], ib in [0,16)
        if (i < 16384) { int j = i & 3; int rest = i >> 2; int t = rest & 255; int ib = rest >> 8;
                         lWhh4[i] = lWhh[t * 64 + ib * 4 + j]; return; }
        i -= 16384;
        if (i < EPAD) { heT[(size_t)128 * EPAD + i] = (_Float16)1.0f; return; }
        i -= EPAD;
        if (i <= N_GRAPHS) {
            if (i == N_GRAPHS) { gstart[i] = N_NODES; return; }
            int lo = 0, hi = N_NODES;
            while (lo < hi) { int mid = (lo + hi) >> 1; if (batch[mid] < i) lo = mid + 1; else hi = mid; }
            gstart[i] = lo;
            return;
        }
        i -= (N_GRAPHS + 1);
        if (i < N_EDGES) { atomicAdd(&deg[dst[i]], 1.f); return; }
    }
}

// ---------------- message passing v13: v10 inner loop, 8-wave blocks for 2x B-reuse ----
// msg[e,f] = sum_c he[e,c] * (x[src_e] @ W_c)[f]; he folded into A-frag.
// Block = 8 waves = 256 edges x one 32-f half: all 8 waves share the same 4KB B
// c-slice per c (32 MFMA per 4KB vs 16 in the 4-wave version) -> per-CU B-miss
// traffic halves. Wave-level work identical to msg_v10 (68 us known-good): depth-2
// ping-pong, single acc chain (VGPR ~56), KS=2 c-split, per-block c-rotation.
__global__ __launch_bounds__(512) void msg_v13(
    const _Float16* __restrict__ Bg, const _Float16* __restrict__ heT,
    const _Float16* __restrict__ xh, const int* __restrict__ src,
    const int* __restrict__ dst, float* __restrict__ agg)
{
    int tid = threadIdx.x;
    int w = tid >> 6, lane = tid & 63;
    int l5 = lane >> 5, l31 = lane & 31;
    int bx = blockIdx.x;
    int ft = bx & 1;                       // f half: 0 or 1
    int eg = bx >> 1;                      // 0..156
    int m0 = eg * 256 + w * 32;            // wave's 32 edges (max 40160+31 < EPAD)
    int KS = gridDim.y, ks = blockIdx.y;
    int c0 = (129 * ks) / KS;
    int c1 = (129 * (ks + 1)) / KS;
    int nc = c1 - c0;

    // persistent x[src] fragment: row = l31, k = kc*16 + l5*8 + j
    union XU { h2 p[4]; half8 v; } xf[4];
    {
        int e = m0 + l31;
        const _Float16* xp = xh + (size_t)src[e] * 64 + l5 * 8;
        xf[0].v = *(const half8*)(xp);
        xf[1].v = *(const half8*)(xp + 16);
        xf[2].v = *(const half8*)(xp + 32);
        xf[3].v = *(const half8*)(xp + 48);
    }

    f32x16 acc = {};
    const _Float16* bbase = Bg + ft * 512 + lane * 8;
    const _Float16* hbase = heT + m0 + l31;

    half8 bA[4], bB[4];
    _Float16 hA, hB;

    auto LOADB = [&](int c, half8* bb, _Float16& hh) {
        const _Float16* bp = bbase + c * 4096;
        bb[0] = *(const half8*)(bp);
        bb[1] = *(const half8*)(bp + 1024);
        bb[2] = *(const half8*)(bp + 2048);
        bb[3] = *(const half8*)(bp + 3072);
        hh = hbase[c * EPAD];
    };
    auto COMP = [&](const half8* bb, _Float16 hh) {
        h2 hv = (h2){hh, hh};
        #pragma unroll
        for (int kc = 0; kc < 4; ++kc) {
            union XU a;
            #pragma unroll
            for (int j = 0; j < 4; ++j) a.p[j] = hv * xf[kc].p[j];
            acc = __builtin_amdgcn_mfma_f32_32x32x16_f16(a.v, bb[kc], acc, 0, 0, 0);
        }
    };

    int cur = bx % nc;                     // rotated start within slice
    LOADB(c0 + cur, bA, hA);
    int done = 1;                          // loads issued
    for (; done + 1 < nc; done += 2) {
        int n1 = (cur + 1 == nc) ? 0 : cur + 1;
        LOADB(c0 + n1, bB, hB);
        COMP(bA, hA);
        int n2 = (n1 + 1 == nc) ? 0 : n1 + 1;
        LOADB(c0 + n2, bA, hA);
        COMP(bB, hB);
        cur = n2;
    }
    if (done < nc) {                       // nc even: one load left
        int n1 = (cur + 1 == nc) ? 0 : cur + 1;
        LOADB(c0 + n1, bB, hB);
        COMP(bA, hA);
        COMP(bB, hB);
    } else {                               // nc odd
        COMP(bA, hA);
    }

    // scatter: D col = f = ft*32 + l31; row = (r&3) + 8*(r>>2) + 4*l5
    int fc = ft * 32 + l31;
    #pragma unroll
    for (int r = 0; r < 16; ++r) {
        int e = m0 + (r & 3) + 8 * (r >> 2) + 4 * l5;
        if (e < N_EDGES)
            atomicAdd(&agg[(size_t)dst[e] * 64 + fc], acc[r]);
    }
}

// ---------------- GRU v2: gate-per-thread, coalesced float4 weight loads ----------------
__global__ __launch_bounds__(192) void gru_v2(float* __restrict__ agg,
    const float* __restrict__ deg, const float* __restrict__ bconv,
    const float* __restrict__ Wih4, const float* __restrict__ Whh4,
    const float* __restrict__ bih, const float* __restrict__ bhh,
    float* __restrict__ hx, _Float16* __restrict__ xh) {
    __shared__ float mS[4][64], hS[4][64];
    __shared__ float aI[4][192], aH[4][192];
    int t = threadIdx.x;
    int n0 = blockIdx.x << 2;
    for (int idx = t; idx < 256; idx += 192) {
        int n = idx >> 6, j = idx & 63;
        size_t ix = (size_t)(n0 + n) * 64 + j;
        float dg = fmaxf(deg[n0 + n], 1.f);
        float m = fmaxf(agg[ix] / dg + bconv[j], 0.f);
        agg[ix] = 0.f;
        mS[n][j] = m;
        hS[n][j] = hx[ix];
    }
    __syncthreads();
    float bi = bih[t], bh = bhh[t];
    float AI[4], AH[4];
    #pragma unroll
    for (int n = 0; n < 4; ++n) { AI[n] = bi; AH[n] = bh; }
    #pragma unroll
    for (int ib = 0; ib < 16; ++ib) {
        f32x4 wi = *(const f32x4*)(Wih4 + ((ib * 192 + t) << 2));
        f32x4 wh = *(const f32x4*)(Whh4 + ((ib * 192 + t) << 2));
        int i0 = ib * 4;
        #pragma unroll
        for (int n = 0; n < 4; ++n) {
            AI[n] = fmaf(mS[n][i0],     wi[0], AI[n]);
            AI[n] = fmaf(mS[n][i0 + 1], wi[1], AI[n]);
            AI[n] = fmaf(mS[n][i0 + 2], wi[2], AI[n]);
            AI[n] = fmaf(mS[n][i0 + 3], wi[3], AI[n]);
            AH[n] = fmaf(hS[n][i0],     wh[0], AH[n]);
            AH[n] = fmaf(hS[n][i0 + 1], wh[1], AH[n]);
            AH[n] = fmaf(hS[n][i0 + 2], wh[2], AH[n]);
            AH[n] = fmaf(hS[n][i0 + 3], wh[3], AH[n]);
        }
    }
    #pragma unroll
    for (int n = 0; n < 4; ++n) { aI[n][t] = AI[n]; aH[n][t] = AH[n]; }
    __syncthreads();
    for (int idx = t; idx < 256; idx += 192) {
        int n = idx >> 6, j = idx & 63;
        float rr = sigm(aI[n][j] + aH[n][j]);
        float zz = sigm(aI[n][64 + j] + aH[n][64 + j]);
        float nn = tanhf(aI[n][128 + j] + rr * aH[n][128 + j]);
        size_t ix = (size_t)(n0 + n) * 64 + j;
        float h = hS[n][j];
        float hnew = (1.f - zz) * nn + zz * h;
        hx[ix] = hnew;
        xh[ix] = (_Float16)hnew;
    }
}

// ---------------- Set2Set v3: gate-per-thread, coalesced float4 weight loads ----------
__global__ __launch_bounds__(256) void s2s_kernel(const float* __restrict__ x,
    const int* __restrict__ gstart,
    const float* __restrict__ WI4,   // [(ib*256+t)*4+j] = lWih[t][ib*4+j], ib<32
    const float* __restrict__ WH4,   // [(ib*256+t)*4+j] = lWhh[t][ib*4+j], ib<16
    const float* __restrict__ bih, const float* __restrict__ bhh,
    float* __restrict__ qstar) {
    __shared__ float st[192];          // q(0..63), r(64..127), h(128..191)
    __shared__ float gl[256];
    __shared__ float redmax[4], redsum[4];
    __shared__ float raccs[4][64];
    int g = blockIdx.x, t = threadIdx.x;
    int w = t >> 6, j = t & 63;
    int s0 = gstart[g], s1 = gstart[g + 1];
    if (t < 192) st[t] = 0.f;
    float cj = 0.f;
    float bsum = bih[t] + bhh[t];
    __syncthreads();
    for (int s = 0; s < 3; ++s) {
        float a0 = bsum;
        #pragma unroll
        for (int ib = 0; ib < 32; ++ib) {
            f32x4 wv = *(const f32x4*)(WI4 + ((ib * 256 + t) << 2));
            int i0 = ib * 4;
            a0 = fmaf(st[i0],     wv[0], a0);
            a0 = fmaf(st[i0 + 1], wv[1], a0);
            a0 = fmaf(st[i0 + 2], wv[2], a0);
            a0 = fmaf(st[i0 + 3], wv[3], a0);
        }
        #pragma unroll
        for (int ib = 0; ib < 16; ++ib) {
            f32x4 wv = *(const f32x4*)(WH4 + ((ib * 256 + t) << 2));
            int i0 = 128 + ib * 4;
            a0 = fmaf(st[i0],     wv[0], a0);
            a0 = fmaf(st[i0 + 1], wv[1], a0);
            a0 = fmaf(st[i0 + 2], wv[2], a0);
            a0 = fmaf(st[i0 + 3], wv[3], a0);
        }
        gl[t] = a0;
        __syncthreads();
        if (t < 64) {
            float ig = sigm(gl[t]);
            float fg = sigm(gl[64 + t]);
            float cg = tanhf(gl[128 + t]);
            float og = sigm(gl[192 + t]);
            cj = fg * cj + ig * cg;
            float hnew = og * tanhf(cj);
            st[t] = hnew;        // q = h
            st[128 + t] = hnew;  // h
        }
        __syncthreads();
        float hj = st[128 + j];
        float pmax = -3.0e38f;
        for (int n = s0 + w; n < s1; n += 4) {
            float v = x[(size_t)n * 64 + j] * hj;
            for (int o = 32; o; o >>= 1) v += __shfl_xor(v, o);
            pmax = fmaxf(pmax, v);
        }
        if (j == 0) redmax[w] = pmax;
        __syncthreads();
        float emax = fmaxf(fmaxf(redmax[0], redmax[1]), fmaxf(redmax[2], redmax[3]));
        float esum = 0.f, racc = 0.f;
        for (int n = s0 + w; n < s1; n += 4) {
            float xv = x[(size_t)n * 64 + j];
            float v = xv * hj;
            for (int o = 32; o; o >>= 1) v += __shfl_xor(v, o);
            float ww = expf(v - emax);
            esum += ww;
            racc = fmaf(ww, xv, racc);
        }
        raccs[w][j] = racc;
        if (j == 0) redsum[w] = esum;
        __syncthreads();
        if (t < 64) {
            float es = redsum[0] + redsum[1] + redsum[2] + redsum[3];
            st[64 + j] = (raccs[0][j] + raccs[1][j] + raccs[2][j] + raccs[3][j]) / es;
        }
        __syncthreads();
    }
    if (t < 64) {
        qstar[g * 128 + t] = st[t];
        qstar[g * 128 + 64 + t] = st[64 + t];
    }
}

// ---------------- head ----------------
__global__ void bn_kernel(const float* __restrict__ qs, const float* __restrict__ gamma,
                          const float* __restrict__ beta, float* __restrict__ out) {
    int c = blockIdx.x, l = threadIdx.x;
    float s = 0.f, ss = 0.f;
    for (int r = l; r < N_GRAPHS; r += 64) {
        float v = qs[r * 128 + c];
        s += v; ss += v * v;
    }
    for (int o = 32; o; o >>= 1) { s += __shfl_xor(s, o); ss += __shfl_xor(ss, o); }
    float mu = s * (1.f / N_GRAPHS);
    float var = ss * (1.f / N_GRAPHS) - mu * mu;
    float inv = rsqrtf(var + 1e-5f);
    float ga = gamma[c], be = beta[c];
    for (int r = l; r < N_GRAPHS; r += 64)
        out[r * 128 + c] = ga * (qs[r * 128 + c] - mu) * inv + be;
}

__global__ __launch_bounds__(512) void head_fused(const float* __restrict__ bno,
    const float* __restrict__ Wm1, const float* __restrict__ bm1,
    const float* __restrict__ Wm2, const float* __restrict__ bm2,
    const float* __restrict__ Wp, const float* __restrict__ bp,
    float* __restrict__ out) {
    __shared__ float row[128];
    __shared__ float y1[512];
    __shared__ float y2[256];
    int g = blockIdx.x, t = threadIdx.x;
    int rot = (g * 17) & 127;
    if (t < 128) row[t] = bno[g * 128 + t];
    __syncthreads();
    float acc = bm1[t];
    for (int s = 0; s < 128; ++s) {
        int i = (s + rot) & 127;
        acc = fmaf(row[i], Wm1[i * MLP1D + t], acc);
    }
    y1[t] = fmaxf(acc, 0.f);
    __syncthreads();
    if (t < 256) {
        float a2 = bm2[t];
        int rot2 = (g * 31) & 511;
        for (int s = 0; s < 512; ++s) {
            int i = (s + rot2) & 511;
            a2 = fmaf(y1[i], Wm2[i * MLP2D + t], a2);
        }
        y2[t] = fmaxf(a2, 0.f);
    }
    __syncthreads();
    if (t < NOUT) {
        float a3 = bp[t];
        int rot3 = (g * 13) & 255;
        for (int s = 0; s < 256; ++s) {
            int i = (s + rot3) & 255;
            a3 = fmaf(y2[i], Wp[i * NOUT + t], a3);
        }
        out[g * NOUT + t] = a3;
    }
}

// ---------------- launch ----------------
extern "C" void kernel_launch(void* const* d_in, const int* in_sizes, int n_in,
                              void* d_out, int out_size, void* d_ws, size_t ws_size,
                              hipStream_t stream) {
    (void)in_sizes; (void)n_in; (void)out_size; (void)ws_size;
    const float* x_feat    = (const float*)d_in[0];
    const float* edge_attr = (const float*)d_in[1];
    const int*   eidx      = (const int*)d_in[2];
    const int*   batch     = (const int*)d_in[3];
    const float* W_lin = (const float*)d_in[4];
    const float* b_lin = (const float*)d_in[5];
    const float* W_e1  = (const float*)d_in[6];
    const float* b_e1  = (const float*)d_in[7];
    const float* W_e2  = (const float*)d_in[8];
    const float* b_e2  = (const float*)d_in[9];
    const float* b_conv= (const float*)d_in[10];
    const float* gWih  = (const float*)d_in[11];
    const float* gWhh  = (const float*)d_in[12];
    const float* gbih  = (const float*)d_in[13];
    const float* gbhh  = (const float*)d_in[14];
    const float* lWih  = (const float*)d_in[15];
    const float* lWhh  = (const float*)d_in[16];
    const float* lbih  = (const float*)d_in[17];
    const float* lbhh  = (const float*)d_in[18];
    const float* bng   = (const float*)d_in[19];
    const float* bnb   = (const float*)d_in[20];
    const float* Wm1   = (const float*)d_in[21];
    const float* bm1   = (const float*)d_in[22];
    const float* Wm2   = (const float*)d_in[23];
    const float* bm2   = (const float*)d_in[24];
    const float* Wp    = (const float*)d_in[25];
    const float* bp    = (const float*)d_in[26];
    float* out = (float*)d_out;

    const int* src = eidx;
    const int* dst = eidx + N_EDGES;

    char* w = (char*)d_ws;
    size_t off = 0;
    auto alloc = [&](size_t bytes) -> char* {
        char* p = w + off; off += (bytes + 255) & ~(size_t)255; return p;
    };
    _Float16* Bg     = (_Float16*)alloc((size_t)129 * 4096 * 2);     // 1.06 MB
    _Float16* heT    = (_Float16*)alloc((size_t)129 * EPAD * 2);     // 10.4 MB
    _Float16* xh     = (_Float16*)alloc((size_t)N_NODES * 64 * 2);   // 2.56 MB
    float* hx        = (float*)alloc((size_t)N_NODES * 64 * 4);      // 5.12 MB
    float* agg       = (float*)alloc((size_t)N_NODES * 64 * 4);      // 5.12 MB (adjacent to deg)
    float* deg       = (float*)alloc((size_t)N_NODES * 4);
    float* gWih4     = (float*)alloc(192 * 64 * 4);
    float* gWhh4     = (float*)alloc(192 * 64 * 4);
    float* lWih4     = (float*)alloc(256 * 128 * 4);
    float* lWhh4     = (float*)alloc(256 * 64 * 4);
    float* qstar     = (float*)alloc((size_t)N_GRAPHS * 128 * 4);
    int*   gst       = (int*)alloc((N_GRAPHS + 1) * 4);
    float* bno       = (float*)alloc((size_t)N_GRAPHS * 128 * 4);
    // total ~25 MB

    // agg (5,120,000 B, 256-aligned) and deg (80,000 B) are adjacent: one memset
    hipMemsetAsync(agg, 0, (size_t)N_NODES * 64 * 4 + (size_t)N_NODES * 4, stream);

    prep_all<<<PREP_BLKS, 256, 0, stream>>>(
        x_feat, W_lin, b_lin, hx, xh,
        edge_attr, W_e1, b_e1, heT,
        W_e2, b_e2, Bg,
        gWih, gWhh, lWih, lWhh, gWih4, gWhh4, lWih4, lWhh4,
        batch, gst, dst, deg);

    for (int r = 0; r < 3; ++r) {
        msg_v13<<<dim3(314, 2), 512, 0, stream>>>(Bg, heT, xh, src, dst, agg);
        gru_v2<<<N_NODES / 4, 192, 0, stream>>>(agg, deg, b_conv, gWih4, gWhh4, gbih, gbhh, hx, xh);
    }

    s2s_kernel<<<N_GRAPHS, 256, 0, stream>>>(hx, gst, lWih4, lWhh4, lbih, lbhh, qstar);

    bn_kernel<<<128, 64, 0, stream>>>(qstar, bng, bnb, bno);
    head_fused<<<N_GRAPHS, 512, 0, stream>>>(bno, Wm1, bm1, Wm2, bm2, Wp, bp, out);
}

// Round 19
// 386.180 us; speedup vs baseline: 1.4701x; 1.0536x over previous
//
#include <hip/hip_runtime.h>
#include <hip/hip_bf16.h>
#include <cstdint>
#include <cstddef>

#define N_NODES 20000
#define N_EDGES 40000
#define EPAD 40192             // 157*256, padded edge count
#define N_GRAPHS 800
#define ATOM 64
#define MLP1D 512
#define MLP2D 256
#define NOUT 34

typedef _Float16 h2 __attribute__((ext_vector_type(2)));
typedef _Float16 half8 __attribute__((ext_vector_type(8)));
typedef float f32x4 __attribute__((ext_vector_type(4)));
typedef float f32x16 __attribute__((ext_vector_type(16)));

__device__ __forceinline__ float sigm(float x) { return 1.f / (1.f + expf(-x)); }

// ---------------- fused prep: lin + heprep + Bg-build + misc ----------------
#define LIN_BLKS 5000
#define HEP_BLKS (EPAD / 64)                  // 628
#define BF_TOTAL (129 * 4096)                 // 528384
#define BF_BLKS ((BF_TOTAL + 255) / 256)      // 2064
#define MISC_TOTAL (12288 + 12288 + 32768 + 16384 + EPAD + (N_GRAPHS + 1) + N_EDGES)
#define MISC_BLKS ((MISC_TOTAL + 255) / 256)
#define PREP_BLKS (LIN_BLKS + HEP_BLKS + BF_BLKS + MISC_BLKS)

__global__ __launch_bounds__(256) void prep_all(
    const float* __restrict__ x_feat, const float* __restrict__ W_lin,
    const float* __restrict__ b_lin, float* __restrict__ hx, _Float16* __restrict__ xh,
    const float* __restrict__ ea, const float* __restrict__ W_e1,
    const float* __restrict__ b_e1, _Float16* __restrict__ heT,
    const float* __restrict__ We2, const float* __restrict__ be2, _Float16* __restrict__ Bg,
    const float* __restrict__ gWih, const float* __restrict__ gWhh,
    const float* __restrict__ lWih, const float* __restrict__ lWhh,
    float* __restrict__ gWih4, float* __restrict__ gWhh4,
    float* __restrict__ lWih4, float* __restrict__ lWhh4,
    const int* __restrict__ batch, int* __restrict__ gstart,
    const int* __restrict__ dst, float* __restrict__ deg) {
    int bx = blockIdx.x;
    if (bx < LIN_BLKS) {
        __shared__ float xr[4][64];
        int ln = threadIdx.x >> 6, j = threadIdx.x & 63;
        int n = (bx << 2) + ln;
        xr[ln][j] = x_feat[(size_t)n * 64 + j];
        __syncthreads();
        float acc = b_lin[j];
        for (int i = 0; i < 64; ++i) acc = fmaf(xr[ln][i], W_lin[i * 64 + j], acc);
        float r = fmaxf(acc, 0.f);
        hx[(size_t)n * 64 + j] = r;
        xh[(size_t)n * 64 + j] = (_Float16)r;
        return;
    }
    bx -= LIN_BLKS;
    if (bx < HEP_BLKS) {
        __shared__ float eaL[64 * 17];
        int e0 = bx * 64;
        for (int idx = threadIdx.x; idx < 1024; idx += 256) {
            int r = idx >> 4, i = idx & 15;
            int e = e0 + r;
            eaL[r * 17 + i] = (e < N_EDGES) ? ea[(size_t)e * 16 + i] : 0.f;
        }
        __syncthreads();
        int w = threadIdx.x >> 6, lane = threadIdx.x & 63;
        for (int c = w; c < 128; c += 4) {
            float acc = b_e1[c];
            #pragma unroll
            for (int i = 0; i < 16; ++i)
                acc = fmaf(eaL[lane * 17 + i], W_e1[i * 128 + c], acc);
            heT[(size_t)c * EPAD + e0 + lane] = (_Float16)fmaxf(acc, 0.f);
        }
        return;
    }
    bx -= HEP_BLKS;
    if (bx < BF_BLKS) {
        // Bg[c][kc][ft][lane][8] fp16 for 32x32x16 MFMA:
        // value = W_c[k][f], k = kc*16 + (lane>>5)*8 + j, f = ft*32 + (lane&31)
        int idx = bx * 256 + threadIdx.x;
        if (idx >= BF_TOTAL) return;
        int j = idx & 7, lane = (idx >> 3) & 63, ft = (idx >> 9) & 1;
        int kc = (idx >> 10) & 3, c = idx >> 12;
        int k = kc * 16 + (lane >> 5) * 8 + j;
        int f = ft * 32 + (lane & 31);
        float v = (c < 128) ? We2[(size_t)c * 4096 + k * 64 + f] : be2[k * 64 + f];
        Bg[idx] = (_Float16)v;
        return;
    }
    bx -= BF_BLKS;
    {
        int i = bx * 256 + threadIdx.x;
        // gWih4[(ib*192+t)*4+j] = gWih[t*64 + ib*4 + j], ib in [0,16)
        if (i < 12288) { int j = i & 3; int rest = i >> 2; int t = rest % 192; int ib = rest / 192;
                         gWih4[i] = gWih[t * 64 + ib * 4 + j]; return; }
        i -= 12288;
        if (i < 12288) { int j = i & 3; int rest = i >> 2; int t = rest % 192; int ib = rest / 192;
                         gWhh4[i] = gWhh[t * 64 + ib * 4 + j]; return; }
        i -= 12288;
        // lWih4[(ib*256+t)*4+j] = lWih[t*128 + ib*4 + j], ib in [0,32)
        if (i < 32768) { int j = i & 3; int rest = i >> 2; int t = rest & 255; int ib = rest >> 8;
                         lWih4[i] = lWih[t * 128 + ib * 4 + j]; return; }
        i -= 32768;
        // lWhh4[(ib*256+t)*4+j] = lWhh[t*64 + ib*4 + j], ib in [0,16)
        if (i < 16384) { int j = i & 3; int rest = i >> 2; int t = rest & 255; int ib = rest >> 8;
                         lWhh4[i] = lWhh[t * 64 + ib * 4 + j]; return; }
        i -= 16384;
        if (i < EPAD) { heT[(size_t)128 * EPAD + i] = (_Float16)1.0f; return; }
        i -= EPAD;
        if (i <= N_GRAPHS) {
            if (i == N_GRAPHS) { gstart[i] = N_NODES; return; }
            int lo = 0, hi = N_NODES;
            while (lo < hi) { int mid = (lo + hi) >> 1; if (batch[mid] < i) lo = mid + 1; else hi = mid; }
            gstart[i] = lo;
            return;
        }
        i -= (N_GRAPHS + 1);
        if (i < N_EDGES) { atomicAdd(&deg[dst[i]], 1.f); return; }
    }
}

// ---------------- message passing v10 (round-14 best: 68 us) + T5 setprio ----------------
// msg[e,f] = sum_c he[e,c] * (x[src_e] @ W_c)[f]; he folded into A-frag.
// Block = 4 waves = 128 edges x one 32-f half; KS=2 c-split; depth-2 ping-pong;
// per-block c-rotation. Waves are barrier-free/independent -> setprio(1) around the
// MFMA cluster (T5 applies to independent-wave kernels, not lockstep ones).
__global__ __launch_bounds__(256) void msg_v10(
    const _Float16* __restrict__ Bg, const _Float16* __restrict__ heT,
    const _Float16* __restrict__ xh, const int* __restrict__ src,
    const int* __restrict__ dst, float* __restrict__ agg)
{
    int tid = threadIdx.x;
    int w = tid >> 6, lane = tid & 63;
    int l5 = lane >> 5, l31 = lane & 31;
    int bx = blockIdx.x;
    int ft = bx & 1;                       // f half: 0 or 1
    int eg = bx >> 1;                      // 0..313
    int m0 = eg * 128 + w * 32;            // wave's 32 edges
    int KS = gridDim.y, ks = blockIdx.y;
    int c0 = (129 * ks) / KS;
    int c1 = (129 * (ks + 1)) / KS;
    int nc = c1 - c0;

    // persistent x[src] fragment: row = l31, k = kc*16 + l5*8 + j
    union XU { h2 p[4]; half8 v; } xf[4];
    {
        int e = m0 + l31;
        const _Float16* xp = xh + (size_t)src[e] * 64 + l5 * 8;
        xf[0].v = *(const half8*)(xp);
        xf[1].v = *(const half8*)(xp + 16);
        xf[2].v = *(const half8*)(xp + 32);
        xf[3].v = *(const half8*)(xp + 48);
    }

    f32x16 acc = {};
    const _Float16* bbase = Bg + ft * 512 + lane * 8;
    const _Float16* hbase = heT + m0 + l31;

    half8 bA[4], bB[4];
    _Float16 hA, hB;

    auto LOADB = [&](int c, half8* bb, _Float16& hh) {
        const _Float16* bp = bbase + c * 4096;
        bb[0] = *(const half8*)(bp);
        bb[1] = *(const half8*)(bp + 1024);
        bb[2] = *(const half8*)(bp + 2048);
        bb[3] = *(const half8*)(bp + 3072);
        hh = hbase[c * EPAD];
    };
    auto COMP = [&](const half8* bb, _Float16 hh) {
        h2 hv = (h2){hh, hh};
        __builtin_amdgcn_s_setprio(1);
        #pragma unroll
        for (int kc = 0; kc < 4; ++kc) {
            union XU a;
            #pragma unroll
            for (int j = 0; j < 4; ++j) a.p[j] = hv * xf[kc].p[j];
            acc = __builtin_amdgcn_mfma_f32_32x32x16_f16(a.v, bb[kc], acc, 0, 0, 0);
        }
        __builtin_amdgcn_s_setprio(0);
    };

    int cur = bx % nc;                     // rotated start within slice
    LOADB(c0 + cur, bA, hA);
    int done = 1;                          // loads issued
    for (; done + 1 < nc; done += 2) {
        int n1 = (cur + 1 == nc) ? 0 : cur + 1;
        LOADB(c0 + n1, bB, hB);
        COMP(bA, hA);
        int n2 = (n1 + 1 == nc) ? 0 : n1 + 1;
        LOADB(c0 + n2, bA, hA);
        COMP(bB, hB);
        cur = n2;
    }
    if (done < nc) {                       // nc even: one load left
        int n1 = (cur + 1 == nc) ? 0 : cur + 1;
        LOADB(c0 + n1, bB, hB);
        COMP(bA, hA);
        COMP(bB, hB);
    } else {                               // nc odd
        COMP(bA, hA);
    }

    // scatter: D col = f = ft*32 + l31; row = (r&3) + 8*(r>>2) + 4*l5
    int fc = ft * 32 + l31;
    #pragma unroll
    for (int r = 0; r < 16; ++r) {
        int e = m0 + (r & 3) + 8 * (r >> 2) + 4 * l5;
        if (e < N_EDGES)
            atomicAdd(&agg[(size_t)dst[e] * 64 + fc], acc[r]);
    }
}

// ---------------- GRU v2: gate-per-thread, coalesced float4 weight loads ----------------
__global__ __launch_bounds__(192) void gru_v2(float* __restrict__ agg,
    const float* __restrict__ deg, const float* __restrict__ bconv,
    const float* __restrict__ Wih4, const float* __restrict__ Whh4,
    const float* __restrict__ bih, const float* __restrict__ bhh,
    float* __restrict__ hx, _Float16* __restrict__ xh) {
    __shared__ float mS[4][64], hS[4][64];
    __shared__ float aI[4][192], aH[4][192];
    int t = threadIdx.x;
    int n0 = blockIdx.x << 2;
    for (int idx = t; idx < 256; idx += 192) {
        int n = idx >> 6, j = idx & 63;
        size_t ix = (size_t)(n0 + n) * 64 + j;
        float dg = fmaxf(deg[n0 + n], 1.f);
        float m = fmaxf(agg[ix] / dg + bconv[j], 0.f);
        agg[ix] = 0.f;
        mS[n][j] = m;
        hS[n][j] = hx[ix];
    }
    __syncthreads();
    float bi = bih[t], bh = bhh[t];
    float AI[4], AH[4];
    #pragma unroll
    for (int n = 0; n < 4; ++n) { AI[n] = bi; AH[n] = bh; }
    #pragma unroll
    for (int ib = 0; ib < 16; ++ib) {
        f32x4 wi = *(const f32x4*)(Wih4 + ((ib * 192 + t) << 2));
        f32x4 wh = *(const f32x4*)(Whh4 + ((ib * 192 + t) << 2));
        int i0 = ib * 4;
        #pragma unroll
        for (int n = 0; n < 4; ++n) {
            AI[n] = fmaf(mS[n][i0],     wi[0], AI[n]);
            AI[n] = fmaf(mS[n][i0 + 1], wi[1], AI[n]);
            AI[n] = fmaf(mS[n][i0 + 2], wi[2], AI[n]);
            AI[n] = fmaf(mS[n][i0 + 3], wi[3], AI[n]);
            AH[n] = fmaf(hS[n][i0],     wh[0], AH[n]);
            AH[n] = fmaf(hS[n][i0 + 1], wh[1], AH[n]);
            AH[n] = fmaf(hS[n][i0 + 2], wh[2], AH[n]);
            AH[n] = fmaf(hS[n][i0 + 3], wh[3], AH[n]);
        }
    }
    #pragma unroll
    for (int n = 0; n < 4; ++n) { aI[n][t] = AI[n]; aH[n][t] = AH[n]; }
    __syncthreads();
    for (int idx = t; idx < 256; idx += 192) {
        int n = idx >> 6, j = idx & 63;
        float rr = sigm(aI[n][j] + aH[n][j]);
        float zz = sigm(aI[n][64 + j] + aH[n][64 + j]);
        float nn = tanhf(aI[n][128 + j] + rr * aH[n][128 + j]);
        size_t ix = (size_t)(n0 + n) * 64 + j;
        float h = hS[n][j];
        float hnew = (1.f - zz) * nn + zz * h;
        hx[ix] = hnew;
        xh[ix] = (_Float16)hnew;
    }
}

// ---------------- Set2Set v3: gate-per-thread, coalesced float4 weight loads ----------
__global__ __launch_bounds__(256) void s2s_kernel(const float* __restrict__ x,
    const int* __restrict__ gstart,
    const float* __restrict__ WI4,   // [(ib*256+t)*4+j] = lWih[t][ib*4+j], ib<32
    const float* __restrict__ WH4,   // [(ib*256+t)*4+j] = lWhh[t][ib*4+j], ib<16
    const float* __restrict__ bih, const float* __restrict__ bhh,
    float* __restrict__ qstar) {
    __shared__ float st[192];          // q(0..63), r(64..127), h(128..191)
    __shared__ float gl[256];
    __shared__ float redmax[4], redsum[4];
    __shared__ float raccs[4][64];
    int g = blockIdx.x, t = threadIdx.x;
    int w = t >> 6, j = t & 63;
    int s0 = gstart[g], s1 = gstart[g + 1];
    if (t < 192) st[t] = 0.f;
    float cj = 0.f;
    float bsum = bih[t] + bhh[t];
    __syncthreads();
    for (int s = 0; s < 3; ++s) {
        float a0 = bsum;
        #pragma unroll
        for (int ib = 0; ib < 32; ++ib) {
            f32x4 wv = *(const f32x4*)(WI4 + ((ib * 256 + t) << 2));
            int i0 = ib * 4;
            a0 = fmaf(st[i0],     wv[0], a0);
            a0 = fmaf(st[i0 + 1], wv[1], a0);
            a0 = fmaf(st[i0 + 2], wv[2], a0);
            a0 = fmaf(st[i0 + 3], wv[3], a0);
        }
        #pragma unroll
        for (int ib = 0; ib < 16; ++ib) {
            f32x4 wv = *(const f32x4*)(WH4 + ((ib * 256 + t) << 2));
            int i0 = 128 + ib * 4;
            a0 = fmaf(st[i0],     wv[0], a0);
            a0 = fmaf(st[i0 + 1], wv[1], a0);
            a0 = fmaf(st[i0 + 2], wv[2], a0);
            a0 = fmaf(st[i0 + 3], wv[3], a0);
        }
        gl[t] = a0;
        __syncthreads();
        if (t < 64) {
            float ig = sigm(gl[t]);
            float fg = sigm(gl[64 + t]);
            float cg = tanhf(gl[128 + t]);
            float og = sigm(gl[192 + t]);
            cj = fg * cj + ig * cg;
            float hnew = og * tanhf(cj);
            st[t] = hnew;        // q = h
            st[128 + t] = hnew;  // h
        }
        __syncthreads();
        float hj = st[128 + j];
        float pmax = -3.0e38f;
        for (int n = s0 + w; n < s1; n += 4) {
            float v = x[(size_t)n * 64 + j] * hj;
            for (int o = 32; o; o >>= 1) v += __shfl_xor(v, o);
            pmax = fmaxf(pmax, v);
        }
        if (j == 0) redmax[w] = pmax;
        __syncthreads();
        float emax = fmaxf(fmaxf(redmax[0], redmax[1]), fmaxf(redmax[2], redmax[3]));
        float esum = 0.f, racc = 0.f;
        for (int n = s0 + w; n < s1; n += 4) {
            float xv = x[(size_t)n * 64 + j];
            float v = xv * hj;
            for (int o = 32; o; o >>= 1) v += __shfl_xor(v, o);
            float ww = expf(v - emax);
            esum += ww;
            racc = fmaf(ww, xv, racc);
        }
        raccs[w][j] = racc;
        if (j == 0) redsum[w] = esum;
        __syncthreads();
        if (t < 64) {
            float es = redsum[0] + redsum[1] + redsum[2] + redsum[3];
            st[64 + j] = (raccs[0][j] + raccs[1][j] + raccs[2][j] + raccs[3][j]) / es;
        }
        __syncthreads();
    }
    if (t < 64) {
        qstar[g * 128 + t] = st[t];
        qstar[g * 128 + 64 + t] = st[64 + t];
    }
}

// ---------------- head ----------------
__global__ void bn_kernel(const float* __restrict__ qs, const float* __restrict__ gamma,
                          const float* __restrict__ beta, float* __restrict__ out) {
    int c = blockIdx.x, l = threadIdx.x;
    float s = 0.f, ss = 0.f;
    for (int r = l; r < N_GRAPHS; r += 64) {
        float v = qs[r * 128 + c];
        s += v; ss += v * v;
    }
    for (int o = 32; o; o >>= 1) { s += __shfl_xor(s, o); ss += __shfl_xor(ss, o); }
    float mu = s * (1.f / N_GRAPHS);
    float var = ss * (1.f / N_GRAPHS) - mu * mu;
    float inv = rsqrtf(var + 1e-5f);
    float ga = gamma[c], be = beta[c];
    for (int r = l; r < N_GRAPHS; r += 64)
        out[r * 128 + c] = ga * (qs[r * 128 + c] - mu) * inv + be;
}

__global__ __launch_bounds__(512) void head_fused(const float* __restrict__ bno,
    const float* __restrict__ Wm1, const float* __restrict__ bm1,
    const float* __restrict__ Wm2, const float* __restrict__ bm2,
    const float* __restrict__ Wp, const float* __restrict__ bp,
    float* __restrict__ out) {
    __shared__ float row[128];
    __shared__ float y1[512];
    __shared__ float y2[256];
    int g = blockIdx.x, t = threadIdx.x;
    int rot = (g * 17) & 127;
    if (t < 128) row[t] = bno[g * 128 + t];
    __syncthreads();
    float acc = bm1[t];
    for (int s = 0; s < 128; ++s) {
        int i = (s + rot) & 127;
        acc = fmaf(row[i], Wm1[i * MLP1D + t], acc);
    }
    y1[t] = fmaxf(acc, 0.f);
    __syncthreads();
    if (t < 256) {
        float a2 = bm2[t];
        int rot2 = (g * 31) & 511;
        for (int s = 0; s < 512; ++s) {
            int i = (s + rot2) & 511;
            a2 = fmaf(y1[i], Wm2[i * MLP2D + t], a2);
        }
        y2[t] = fmaxf(a2, 0.f);
    }
    __syncthreads();
    if (t < NOUT) {
        float a3 = bp[t];
        int rot3 = (g * 13) & 255;
        for (int s = 0; s < 256; ++s) {
            int i = (s + rot3) & 255;
            a3 = fmaf(y2[i], Wp[i * NOUT + t], a3);
        }
        out[g * NOUT + t] = a3;
    }
}

// ---------------- launch ----------------
extern "C" void kernel_launch(void* const* d_in, const int* in_sizes, int n_in,
                              void* d_out, int out_size, void* d_ws, size_t ws_size,
                              hipStream_t stream) {
    (void)in_sizes; (void)n_in; (void)out_size; (void)ws_size;
    const float* x_feat    = (const float*)d_in[0];
    const float* edge_attr = (const float*)d_in[1];
    const int*   eidx      = (const int*)d_in[2];
    const int*   batch     = (const int*)d_in[3];
    const float* W_lin = (const float*)d_in[4];
    const float* b_lin = (const float*)d_in[5];
    const float* W_e1  = (const float*)d_in[6];
    const float* b_e1  = (const float*)d_in[7];
    const float* W_e2  = (const float*)d_in[8];
    const float* b_e2  = (const float*)d_in[9];
    const float* b_conv= (const float*)d_in[10];
    const float* gWih  = (const float*)d_in[11];
    const float* gWhh  = (const float*)d_in[12];
    const float* gbih  = (const float*)d_in[13];
    const float* gbhh  = (const float*)d_in[14];
    const float* lWih  = (const float*)d_in[15];
    const float* lWhh  = (const float*)d_in[16];
    const float* lbih  = (const float*)d_in[17];
    const float* lbhh  = (const float*)d_in[18];
    const float* bng   = (const float*)d_in[19];
    const float* bnb   = (const float*)d_in[20];
    const float* Wm1   = (const float*)d_in[21];
    const float* bm1   = (const float*)d_in[22];
    const float* Wm2   = (const float*)d_in[23];
    const float* bm2   = (const float*)d_in[24];
    const float* Wp    = (const float*)d_in[25];
    const float* bp    = (const float*)d_in[26];
    float* out = (float*)d_out;

    const int* src = eidx;
    const int* dst = eidx + N_EDGES;

    char* w = (char*)d_ws;
    size_t off = 0;
    auto alloc = [&](size_t bytes) -> char* {
        char* p = w + off; off += (bytes + 255) & ~(size_t)255; return p;
    };
    _Float16* Bg     = (_Float16*)alloc((size_t)129 * 4096 * 2);     // 1.06 MB
    _Float16* heT    = (_Float16*)alloc((size_t)129 * EPAD * 2);     // 10.4 MB
    _Float16* xh     = (_Float16*)alloc((size_t)N_NODES * 64 * 2);   // 2.56 MB
    float* hx        = (float*)alloc((size_t)N_NODES * 64 * 4);      // 5.12 MB
    float* agg       = (float*)alloc((size_t)N_NODES * 64 * 4);      // 5.12 MB (adjacent to deg)
    float* deg       = (float*)alloc((size_t)N_NODES * 4);
    float* gWih4     = (float*)alloc(192 * 64 * 4);
    float* gWhh4     = (float*)alloc(192 * 64 * 4);
    float* lWih4     = (float*)alloc(256 * 128 * 4);
    float* lWhh4     = (float*)alloc(256 * 64 * 4);
    float* qstar     = (float*)alloc((size_t)N_GRAPHS * 128 * 4);
    int*   gst       = (int*)alloc((N_GRAPHS + 1) * 4);
    float* bno       = (float*)alloc((size_t)N_GRAPHS * 128 * 4);
    // total ~25 MB

    // agg (5,120,000 B, 256-aligned) and deg (80,000 B) are adjacent: one memset
    hipMemsetAsync(agg, 0, (size_t)N_NODES * 64 * 4 + (size_t)N_NODES * 4, stream);

    prep_all<<<PREP_BLKS, 256, 0, stream>>>(
        x_feat, W_lin, b_lin, hx, xh,
        edge_attr, W_e1, b_e1, heT,
        W_e2, b_e2, Bg,
        gWih, gWhh, lWih, lWhh, gWih4, gWhh4, lWih4, lWhh4,
        batch, gst, dst, deg);

    for (int r = 0; r < 3; ++r) {
        msg_v10<<<dim3(628, 2), 256, 0, stream>>>(Bg, heT, xh, src, dst, agg);
        gru_v2<<<N_NODES / 4, 192, 0, stream>>>(agg, deg, b_conv, gWih4, gWhh4, gbih, gbhh, hx, xh);
    }

    s2s_kernel<<<N_GRAPHS, 256, 0, stream>>>(hx, gst, lWih4, lWhh4, lbih, lbhh, qstar);

    bn_kernel<<<128, 64, 0, stream>>>(qstar, bng, bnb, bno);
    head_fused<<<N_GRAPHS, 512, 0, stream>>>(bno, Wm1, bm1, Wm2, bm2, Wp, bp, out);
}

// Round 20
// 380.861 us; speedup vs baseline: 1.4906x; 1.0140x over previous
//
#include <hip/hip_runtime.h>
#include <hip/hip_bf16.h>
#include <cstdint>
#include <cstddef>

#define N_NODES 20000
#define N_EDGES 40000
#define EPAD 40192             // 157*256, padded edge count
#define N_GRAPHS 800
#define ATOM 64
#define MLP1D 512
#define MLP2D 256
#define NOUT 34

typedef _Float16 h2 __attribute__((ext_vector_type(2)));
typedef _Float16 half8 __attribute__((ext_vector_type(8)));
typedef float f32x4 __attribute__((ext_vector_type(4)));
typedef float f32x16 __attribute__((ext_vector_type(16)));

__device__ __forceinline__ float sigm(float x) { return 1.f / (1.f + expf(-x)); }

// ---------------- fused prep: lin + heprep + Bg-build + misc ----------------
#define LIN_BLKS 5000
#define HEP_BLKS (EPAD / 64)                  // 628
#define BF_TOTAL (129 * 4096)                 // 528384
#define BF_BLKS ((BF_TOTAL + 255) / 256)      // 2064
#define MISC_TOTAL (12288 + 12288 + 32768 + 16384 + EPAD + (N_GRAPHS + 1) + N_EDGES)
#define MISC_BLKS ((MISC_TOTAL + 255) / 256)
#define PREP_BLKS (LIN_BLKS + HEP_BLKS + BF_BLKS + MISC_BLKS)

__global__ __launch_bounds__(256) void prep_all(
    const float* __restrict__ x_feat, const float* __restrict__ W_lin,
    const float* __restrict__ b_lin, float* __restrict__ hx, _Float16* __restrict__ xh,
    const float* __restrict__ ea, const float* __restrict__ W_e1,
    const float* __restrict__ b_e1, _Float16* __restrict__ heT,
    const float* __restrict__ We2, const float* __restrict__ be2, _Float16* __restrict__ Bg,
    const float* __restrict__ gWih, const float* __restrict__ gWhh,
    const float* __restrict__ lWih, const float* __restrict__ lWhh,
    float* __restrict__ gWih4, float* __restrict__ gWhh4,
    float* __restrict__ lWih4, float* __restrict__ lWhh4,
    const int* __restrict__ batch, int* __restrict__ gstart,
    const int* __restrict__ dst, float* __restrict__ deg) {
    int bx = blockIdx.x;
    if (bx < LIN_BLKS) {
        __shared__ float xr[4][64];
        int ln = threadIdx.x >> 6, j = threadIdx.x & 63;
        int n = (bx << 2) + ln;
        xr[ln][j] = x_feat[(size_t)n * 64 + j];
        __syncthreads();
        float acc = b_lin[j];
        for (int i = 0; i < 64; ++i) acc = fmaf(xr[ln][i], W_lin[i * 64 + j], acc);
        float r = fmaxf(acc, 0.f);
        hx[(size_t)n * 64 + j] = r;
        xh[(size_t)n * 64 + j] = (_Float16)r;
        return;
    }
    bx -= LIN_BLKS;
    if (bx < HEP_BLKS) {
        __shared__ float eaL[64 * 17];
        int e0 = bx * 64;
        for (int idx = threadIdx.x; idx < 1024; idx += 256) {
            int r = idx >> 4, i = idx & 15;
            int e = e0 + r;
            eaL[r * 17 + i] = (e < N_EDGES) ? ea[(size_t)e * 16 + i] : 0.f;
        }
        __syncthreads();
        int w = threadIdx.x >> 6, lane = threadIdx.x & 63;
        for (int c = w; c < 128; c += 4) {
            float acc = b_e1[c];
            #pragma unroll
            for (int i = 0; i < 16; ++i)
                acc = fmaf(eaL[lane * 17 + i], W_e1[i * 128 + c], acc);
            heT[(size_t)c * EPAD + e0 + lane] = (_Float16)fmaxf(acc, 0.f);
        }
        return;
    }
    bx -= HEP_BLKS;
    if (bx < BF_BLKS) {
        // Bg[c][kc][ft][lane][8] fp16 for 32x32x16 MFMA:
        // value = W_c[k][f], k = kc*16 + (lane>>5)*8 + j, f = ft*32 + (lane&31)
        int idx = bx * 256 + threadIdx.x;
        if (idx >= BF_TOTAL) return;
        int j = idx & 7, lane = (idx >> 3) & 63, ft = (idx >> 9) & 1;
        int kc = (idx >> 10) & 3, c = idx >> 12;
        int k = kc * 16 + (lane >> 5) * 8 + j;
        int f = ft * 32 + (lane & 31);
        float v = (c < 128) ? We2[(size_t)c * 4096 + k * 64 + f] : be2[k * 64 + f];
        Bg[idx] = (_Float16)v;
        return;
    }
    bx -= BF_BLKS;
    {
        int i = bx * 256 + threadIdx.x;
        // gWih4[(ib*192+t)*4+j] = gWih[t*64 + ib*4 + j], ib in [0,16)
        if (i < 12288) { int j = i & 3; int rest = i >> 2; int t = rest % 192; int ib = rest / 192;
                         gWih4[i] = gWih[t * 64 + ib * 4 + j]; return; }
        i -= 12288;
        if (i < 12288) { int j = i & 3; int rest = i >> 2; int t = rest % 192; int ib = rest / 192;
                         gWhh4[i] = gWhh[t * 64 + ib * 4 + j]; return; }
        i -= 12288;
        // lWih4[(ib*256+t)*4+j] = lWih[t*128 + ib*4 + j], ib in [0,32)
        if (i < 32768) { int j = i & 3; int rest = i >> 2; int t = rest & 255; int ib = rest >> 8;
                         lWih4[i] = lWih[t * 128 + ib * 4 + j]; return; }
        i -= 32768;
        // lWhh4[(ib*256+t)*4+j] = lWhh[t*64 + ib*4 + j], ib in [0,16)
        if (i < 16384) { int j = i & 3; int rest = i >> 2; int t = rest & 255; int ib = rest >> 8;
                         lWhh4[i] = lWhh[t * 64 + ib * 4 + j]; return; }
        i -= 16384;
        if (i < EPAD) { heT[(size_t)128 * EPAD + i] = (_Float16)1.0f; return; }
        i -= EPAD;
        if (i <= N_GRAPHS) {
            if (i == N_GRAPHS) { gstart[i] = N_NODES; return; }
            int lo = 0, hi = N_NODES;
            while (lo < hi) { int mid = (lo + hi) >> 1; if (batch[mid] < i) lo = mid + 1; else hi = mid; }
            gstart[i] = lo;
            return;
        }
        i -= (N_GRAPHS + 1);
        if (i < N_EDGES) { atomicAdd(&deg[dst[i]], 1.f); return; }
    }
}

// ---------------- message passing v10 (round-14 best config: 68 us/dispatch) ----------------
// msg[e,f] = sum_c he[e,c] * (x[src_e] @ W_c)[f]; he folded into A-frag.
// Block = 4 waves = 128 edges x one 32-f half; KS=2 c-split; depth-2 ping-pong;
// per-block c-rotation. NOTE: setprio (r19) measured -6% here -> removed.
// Structural floor validated across 7 configs {KS,depth,acc,waves/block,MFMA shape,setprio}.
__global__ __launch_bounds__(256) void msg_v10(
    const _Float16* __restrict__ Bg, const _Float16* __restrict__ heT,
    const _Float16* __restrict__ xh, const int* __restrict__ src,
    const int* __restrict__ dst, float* __restrict__ agg)
{
    int tid = threadIdx.x;
    int w = tid >> 6, lane = tid & 63;
    int l5 = lane >> 5, l31 = lane & 31;
    int bx = blockIdx.x;
    int ft = bx & 1;                       // f half: 0 or 1
    int eg = bx >> 1;                      // 0..313
    int m0 = eg * 128 + w * 32;            // wave's 32 edges
    int KS = gridDim.y, ks = blockIdx.y;
    int c0 = (129 * ks) / KS;
    int c1 = (129 * (ks + 1)) / KS;
    int nc = c1 - c0;

    // persistent x[src] fragment: row = l31, k = kc*16 + l5*8 + j
    union XU { h2 p[4]; half8 v; } xf[4];
    {
        int e = m0 + l31;
        const _Float16* xp = xh + (size_t)src[e] * 64 + l5 * 8;
        xf[0].v = *(const half8*)(xp);
        xf[1].v = *(const half8*)(xp + 16);
        xf[2].v = *(const half8*)(xp + 32);
        xf[3].v = *(const half8*)(xp + 48);
    }

    f32x16 acc = {};
    const _Float16* bbase = Bg + ft * 512 + lane * 8;
    const _Float16* hbase = heT + m0 + l31;

    half8 bA[4], bB[4];
    _Float16 hA, hB;

    auto LOADB = [&](int c, half8* bb, _Float16& hh) {
        const _Float16* bp = bbase + c * 4096;
        bb[0] = *(const half8*)(bp);
        bb[1] = *(const half8*)(bp + 1024);
        bb[2] = *(const half8*)(bp + 2048);
        bb[3] = *(const half8*)(bp + 3072);
        hh = hbase[c * EPAD];
    };
    auto COMP = [&](const half8* bb, _Float16 hh) {
        h2 hv = (h2){hh, hh};
        #pragma unroll
        for (int kc = 0; kc < 4; ++kc) {
            union XU a;
            #pragma unroll
            for (int j = 0; j < 4; ++j) a.p[j] = hv * xf[kc].p[j];
            acc = __builtin_amdgcn_mfma_f32_32x32x16_f16(a.v, bb[kc], acc, 0, 0, 0);
        }
    };

    int cur = bx % nc;                     // rotated start within slice
    LOADB(c0 + cur, bA, hA);
    int done = 1;                          // loads issued
    for (; done + 1 < nc; done += 2) {
        int n1 = (cur + 1 == nc) ? 0 : cur + 1;
        LOADB(c0 + n1, bB, hB);
        COMP(bA, hA);
        int n2 = (n1 + 1 == nc) ? 0 : n1 + 1;
        LOADB(c0 + n2, bA, hA);
        COMP(bB, hB);
        cur = n2;
    }
    if (done < nc) {                       // nc even: one load left
        int n1 = (cur + 1 == nc) ? 0 : cur + 1;
        LOADB(c0 + n1, bB, hB);
        COMP(bA, hA);
        COMP(bB, hB);
    } else {                               // nc odd
        COMP(bA, hA);
    }

    // scatter: D col = f = ft*32 + l31; row = (r&3) + 8*(r>>2) + 4*l5
    int fc = ft * 32 + l31;
    #pragma unroll
    for (int r = 0; r < 16; ++r) {
        int e = m0 + (r & 3) + 8 * (r >> 2) + 4 * l5;
        if (e < N_EDGES)
            atomicAdd(&agg[(size_t)dst[e] * 64 + fc], acc[r]);
    }
}

// ---------------- GRU v2: gate-per-thread, coalesced float4 weight loads ----------------
__global__ __launch_bounds__(192) void gru_v2(float* __restrict__ agg,
    const float* __restrict__ deg, const float* __restrict__ bconv,
    const float* __restrict__ Wih4, const float* __restrict__ Whh4,
    const float* __restrict__ bih, const float* __restrict__ bhh,
    float* __restrict__ hx, _Float16* __restrict__ xh) {
    __shared__ float mS[4][64], hS[4][64];
    __shared__ float aI[4][192], aH[4][192];
    int t = threadIdx.x;
    int n0 = blockIdx.x << 2;
    for (int idx = t; idx < 256; idx += 192) {
        int n = idx >> 6, j = idx & 63;
        size_t ix = (size_t)(n0 + n) * 64 + j;
        float dg = fmaxf(deg[n0 + n], 1.f);
        float m = fmaxf(agg[ix] / dg + bconv[j], 0.f);
        agg[ix] = 0.f;
        mS[n][j] = m;
        hS[n][j] = hx[ix];
    }
    __syncthreads();
    float bi = bih[t], bh = bhh[t];
    float AI[4], AH[4];
    #pragma unroll
    for (int n = 0; n < 4; ++n) { AI[n] = bi; AH[n] = bh; }
    #pragma unroll
    for (int ib = 0; ib < 16; ++ib) {
        f32x4 wi = *(const f32x4*)(Wih4 + ((ib * 192 + t) << 2));
        f32x4 wh = *(const f32x4*)(Whh4 + ((ib * 192 + t) << 2));
        int i0 = ib * 4;
        #pragma unroll
        for (int n = 0; n < 4; ++n) {
            AI[n] = fmaf(mS[n][i0],     wi[0], AI[n]);
            AI[n] = fmaf(mS[n][i0 + 1], wi[1], AI[n]);
            AI[n] = fmaf(mS[n][i0 + 2], wi[2], AI[n]);
            AI[n] = fmaf(mS[n][i0 + 3], wi[3], AI[n]);
            AH[n] = fmaf(hS[n][i0],     wh[0], AH[n]);
            AH[n] = fmaf(hS[n][i0 + 1], wh[1], AH[n]);
            AH[n] = fmaf(hS[n][i0 + 2], wh[2], AH[n]);
            AH[n] = fmaf(hS[n][i0 + 3], wh[3], AH[n]);
        }
    }
    #pragma unroll
    for (int n = 0; n < 4; ++n) { aI[n][t] = AI[n]; aH[n][t] = AH[n]; }
    __syncthreads();
    for (int idx = t; idx < 256; idx += 192) {
        int n = idx >> 6, j = idx & 63;
        float rr = sigm(aI[n][j] + aH[n][j]);
        float zz = sigm(aI[n][64 + j] + aH[n][64 + j]);
        float nn = tanhf(aI[n][128 + j] + rr * aH[n][128 + j]);
        size_t ix = (size_t)(n0 + n) * 64 + j;
        float h = hS[n][j];
        float hnew = (1.f - zz) * nn + zz * h;
        hx[ix] = hnew;
        xh[ix] = (_Float16)hnew;
    }
}

// ---------------- Set2Set v3: gate-per-thread, coalesced float4 weight loads ----------
__global__ __launch_bounds__(256) void s2s_kernel(const float* __restrict__ x,
    const int* __restrict__ gstart,
    const float* __restrict__ WI4,   // [(ib*256+t)*4+j] = lWih[t][ib*4+j], ib<32
    const float* __restrict__ WH4,   // [(ib*256+t)*4+j] = lWhh[t][ib*4+j], ib<16
    const float* __restrict__ bih, const float* __restrict__ bhh,
    float* __restrict__ qstar) {
    __shared__ float st[192];          // q(0..63), r(64..127), h(128..191)
    __shared__ float gl[256];
    __shared__ float redmax[4], redsum[4];
    __shared__ float raccs[4][64];
    int g = blockIdx.x, t = threadIdx.x;
    int w = t >> 6, j = t & 63;
    int s0 = gstart[g], s1 = gstart[g + 1];
    if (t < 192) st[t] = 0.f;
    float cj = 0.f;
    float bsum = bih[t] + bhh[t];
    __syncthreads();
    for (int s = 0; s < 3; ++s) {
        float a0 = bsum;
        #pragma unroll
        for (int ib = 0; ib < 32; ++ib) {
            f32x4 wv = *(const f32x4*)(WI4 + ((ib * 256 + t) << 2));
            int i0 = ib * 4;
            a0 = fmaf(st[i0],     wv[0], a0);
            a0 = fmaf(st[i0 + 1], wv[1], a0);
            a0 = fmaf(st[i0 + 2], wv[2], a0);
            a0 = fmaf(st[i0 + 3], wv[3], a0);
        }
        #pragma unroll
        for (int ib = 0; ib < 16; ++ib) {
            f32x4 wv = *(const f32x4*)(WH4 + ((ib * 256 + t) << 2));
            int i0 = 128 + ib * 4;
            a0 = fmaf(st[i0],     wv[0], a0);
            a0 = fmaf(st[i0 + 1], wv[1], a0);
            a0 = fmaf(st[i0 + 2], wv[2], a0);
            a0 = fmaf(st[i0 + 3], wv[3], a0);
        }
        gl[t] = a0;
        __syncthreads();
        if (t < 64) {
            float ig = sigm(gl[t]);
            float fg = sigm(gl[64 + t]);
            float cg = tanhf(gl[128 + t]);
            float og = sigm(gl[192 + t]);
            cj = fg * cj + ig * cg;
            float hnew = og * tanhf(cj);
            st[t] = hnew;        // q = h
            st[128 + t] = hnew;  // h
        }
        __syncthreads();
        float hj = st[128 + j];
        float pmax = -3.0e38f;
        for (int n = s0 + w; n < s1; n += 4) {
            float v = x[(size_t)n * 64 + j] * hj;
            for (int o = 32; o; o >>= 1) v += __shfl_xor(v, o);
            pmax = fmaxf(pmax, v);
        }
        if (j == 0) redmax[w] = pmax;
        __syncthreads();
        float emax = fmaxf(fmaxf(redmax[0], redmax[1]), fmaxf(redmax[2], redmax[3]));
        float esum = 0.f, racc = 0.f;
        for (int n = s0 + w; n < s1; n += 4) {
            float xv = x[(size_t)n * 64 + j];
            float v = xv * hj;
            for (int o = 32; o; o >>= 1) v += __shfl_xor(v, o);
            float ww = expf(v - emax);
            esum += ww;
            racc = fmaf(ww, xv, racc);
        }
        raccs[w][j] = racc;
        if (j == 0) redsum[w] = esum;
        __syncthreads();
        if (t < 64) {
            float es = redsum[0] + redsum[1] + redsum[2] + redsum[3];
            st[64 + j] = (raccs[0][j] + raccs[1][j] + raccs[2][j] + raccs[3][j]) / es;
        }
        __syncthreads();
    }
    if (t < 64) {
        qstar[g * 128 + t] = st[t];
        qstar[g * 128 + 64 + t] = st[64 + t];
    }
}

// ---------------- head ----------------
__global__ void bn_kernel(const float* __restrict__ qs, const float* __restrict__ gamma,
                          const float* __restrict__ beta, float* __restrict__ out) {
    int c = blockIdx.x, l = threadIdx.x;
    float s = 0.f, ss = 0.f;
    for (int r = l; r < N_GRAPHS; r += 64) {
        float v = qs[r * 128 + c];
        s += v; ss += v * v;
    }
    for (int o = 32; o; o >>= 1) { s += __shfl_xor(s, o); ss += __shfl_xor(ss, o); }
    float mu = s * (1.f / N_GRAPHS);
    float var = ss * (1.f / N_GRAPHS) - mu * mu;
    float inv = rsqrtf(var + 1e-5f);
    float ga = gamma[c], be = beta[c];
    for (int r = l; r < N_GRAPHS; r += 64)
        out[r * 128 + c] = ga * (qs[r * 128 + c] - mu) * inv + be;
}

__global__ __launch_bounds__(512) void head_fused(const float* __restrict__ bno,
    const float* __restrict__ Wm1, const float* __restrict__ bm1,
    const float* __restrict__ Wm2, const float* __restrict__ bm2,
    const float* __restrict__ Wp, const float* __restrict__ bp,
    float* __restrict__ out) {
    __shared__ float row[128];
    __shared__ float y1[512];
    __shared__ float y2[256];
    int g = blockIdx.x, t = threadIdx.x;
    int rot = (g * 17) & 127;
    if (t < 128) row[t] = bno[g * 128 + t];
    __syncthreads();
    float acc = bm1[t];
    for (int s = 0; s < 128; ++s) {
        int i = (s + rot) & 127;
        acc = fmaf(row[i], Wm1[i * MLP1D + t], acc);
    }
    y1[t] = fmaxf(acc, 0.f);
    __syncthreads();
    if (t < 256) {
        float a2 = bm2[t];
        int rot2 = (g * 31) & 511;
        for (int s = 0; s < 512; ++s) {
            int i = (s + rot2) & 511;
            a2 = fmaf(y1[i], Wm2[i * MLP2D + t], a2);
        }
        y2[t] = fmaxf(a2, 0.f);
    }
    __syncthreads();
    if (t < NOUT) {
        float a3 = bp[t];
        int rot3 = (g * 13) & 255;
        for (int s = 0; s < 256; ++s) {
            int i = (s + rot3) & 255;
            a3 = fmaf(y2[i], Wp[i * NOUT + t], a3);
        }
        out[g * NOUT + t] = a3;
    }
}

// ---------------- launch ----------------
extern "C" void kernel_launch(void* const* d_in, const int* in_sizes, int n_in,
                              void* d_out, int out_size, void* d_ws, size_t ws_size,
                              hipStream_t stream) {
    (void)in_sizes; (void)n_in; (void)out_size; (void)ws_size;
    const float* x_feat    = (const float*)d_in[0];
    const float* edge_attr = (const float*)d_in[1];
    const int*   eidx      = (const int*)d_in[2];
    const int*   batch     = (const int*)d_in[3];
    const float* W_lin = (const float*)d_in[4];
    const float* b_lin = (const float*)d_in[5];
    const float* W_e1  = (const float*)d_in[6];
    const float* b_e1  = (const float*)d_in[7];
    const float* W_e2  = (const float*)d_in[8];
    const float* b_e2  = (const float*)d_in[9];
    const float* b_conv= (const float*)d_in[10];
    const float* gWih  = (const float*)d_in[11];
    const float* gWhh  = (const float*)d_in[12];
    const float* gbih  = (const float*)d_in[13];
    const float* gbhh  = (const float*)d_in[14];
    const float* lWih  = (const float*)d_in[15];
    const float* lWhh  = (const float*)d_in[16];
    const float* lbih  = (const float*)d_in[17];
    const float* lbhh  = (const float*)d_in[18];
    const float* bng   = (const float*)d_in[19];
    const float* bnb   = (const float*)d_in[20];
    const float* Wm1   = (const float*)d_in[21];
    const float* bm1   = (const float*)d_in[22];
    const float* Wm2   = (const float*)d_in[23];
    const float* bm2   = (const float*)d_in[24];
    const float* Wp    = (const float*)d_in[25];
    const float* bp    = (const float*)d_in[26];
    float* out = (float*)d_out;

    const int* src = eidx;
    const int* dst = eidx + N_EDGES;

    char* w = (char*)d_ws;
    size_t off = 0;
    auto alloc = [&](size_t bytes) -> char* {
        char* p = w + off; off += (bytes + 255) & ~(size_t)255; return p;
    };
    _Float16* Bg     = (_Float16*)alloc((size_t)129 * 4096 * 2);     // 1.06 MB
    _Float16* heT    = (_Float16*)alloc((size_t)129 * EPAD * 2);     // 10.4 MB
    _Float16* xh     = (_Float16*)alloc((size_t)N_NODES * 64 * 2);   // 2.56 MB
    float* hx        = (float*)alloc((size_t)N_NODES * 64 * 4);      // 5.12 MB
    float* agg       = (float*)alloc((size_t)N_NODES * 64 * 4);      // 5.12 MB (adjacent to deg)
    float* deg       = (float*)alloc((size_t)N_NODES * 4);
    float* gWih4     = (float*)alloc(192 * 64 * 4);
    float* gWhh4     = (float*)alloc(192 * 64 * 4);
    float* lWih4     = (float*)alloc(256 * 128 * 4);
    float* lWhh4     = (float*)alloc(256 * 64 * 4);
    float* qstar     = (float*)alloc((size_t)N_GRAPHS * 128 * 4);
    int*   gst       = (int*)alloc((N_GRAPHS + 1) * 4);
    float* bno       = (float*)alloc((size_t)N_GRAPHS * 128 * 4);
    // total ~25 MB

    // agg (5,120,000 B, 256-aligned) and deg (80,000 B) are adjacent: one memset
    hipMemsetAsync(agg, 0, (size_t)N_NODES * 64 * 4 + (size_t)N_NODES * 4, stream);

    prep_all<<<PREP_BLKS, 256, 0, stream>>>(
        x_feat, W_lin, b_lin, hx, xh,
        edge_attr, W_e1, b_e1, heT,
        W_e2, b_e2, Bg,
        gWih, gWhh, lWih, lWhh, gWih4, gWhh4, lWih4, lWhh4,
        batch, gst, dst, deg);

    for (int r = 0; r < 3; ++r) {
        msg_v10<<<dim3(628, 2), 256, 0, stream>>>(Bg, heT, xh, src, dst, agg);
        gru_v2<<<N_NODES / 4, 192, 0, stream>>>(agg, deg, b_conv, gWih4, gWhh4, gbih, gbhh, hx, xh);
    }

    s2s_kernel<<<N_GRAPHS, 256, 0, stream>>>(hx, gst, lWih4, lWhh4, lbih, lbhh, qstar);

    bn_kernel<<<128, 64, 0, stream>>>(qstar, bng, bnb, bno);
    head_fused<<<N_GRAPHS, 512, 0, stream>>>(bno, Wm1, bm1, Wm2, bm2, Wp, bp, out);
}